// Round 7
// baseline (248.522 us; speedup 1.0000x reference)
//
#include <hip/hip_runtime.h>
#include <hip/hip_bf16.h>
#include <math.h>

#define SCALE_Q 0.25504522f  // 1/sqrt(32) * log2(e)  (Q pre-scale for exp2 softmax)

typedef unsigned short u16;
typedef unsigned int u32;
typedef __attribute__((ext_vector_type(8))) short bshort8;
typedef __attribute__((ext_vector_type(4))) short sshort4;
typedef __attribute__((ext_vector_type(4))) float f32x4;
typedef __attribute__((ext_vector_type(4))) u32 u32x4;

__device__ inline u16 f2b(float f) {  // fp32 -> bf16 RNE
    union { float f; uint32_t u; } c;
    c.f = f;
    uint32_t u = c.u;
    return (u16)((u + 0x7fffu + ((u >> 16) & 1u)) >> 16);
}

__device__ __forceinline__ u32 cvtpk(float a, float b) {  // {lo=bf16(a), hi=bf16(b)}
    u32 r;
    asm("v_cvt_pk_bf16_f32 %0, %1, %2" : "=v"(r) : "v"(a), "v"(b));
    return r;
}

__device__ __forceinline__ float exp2c(float s) {  // 2^min(s,100)
    float c = fminf(s, 100.f);
    float r;
    asm("v_exp_f32 %0, %1" : "=v"(r) : "v"(c));
    return r;
}

__device__ inline void gload_lds16(const void* g, void* lds) {
    __builtin_amdgcn_global_load_lds(
        (const __attribute__((address_space(1))) void*)g,
        (__attribute__((address_space(3))) void*)lds, 16, 0, 0);
}

// ---------------- batched fp32->bf16 convert (11 weights + x) ----------------
struct WSrc { const float* p[12]; };
__global__ __launch_bounds__(256) void wconv_kernel(WSrc s, u16* __restrict__ dst) {
    long e = ((long)blockIdx.x * 256 + threadIdx.x) * 4;
    if (e >= 6553600) return;
    int w; long base;
    if (e < 2359296)      { w = (int)(e >> 18); base = (long)w << 18; }
    else if (e < 3407872) { w = 9;  base = 2359296; }
    else if (e < 4456448) { w = 10; base = 3407872; }
    else                  { w = 11; base = 4456448; }
    float4 v = *(const float4*)(s.p[w] + (e - base));
    dst[e + 0] = f2b(v.x); dst[e + 1] = f2b(v.y);
    dst[e + 2] = f2b(v.z); dst[e + 3] = f2b(v.w);
}

// ---------------- window |max-min| + eps -> transposed bf16 [b][n][c] ----------------
__global__ __launch_bounds__(256) void win_kernel(const float* __restrict__ G,
                                                  u16* __restrict__ Rt, int total) {
    int i = blockIdx.x * 256 + threadIdx.x;
    if (i >= total) return;
    const float4* p = reinterpret_cast<const float4*>(G) + (size_t)i * 2;
    float4 a = p[0], b = p[1];
    float mx = fmaxf(fmaxf(fmaxf(a.x, a.y), fmaxf(a.z, a.w)),
                     fmaxf(fmaxf(b.x, b.y), fmaxf(b.z, b.w)));
    float mn = fminf(fminf(fminf(a.x, a.y), fminf(a.z, a.w)),
                     fminf(fminf(b.x, b.y), fminf(b.z, b.w)));
    int b_ = i >> 18, c = (i >> 9) & 511, n = i & 511;
    Rt[((long)(b_ * 512 + n) << 9) + c] = f2b(fabsf(mx - mn) + 1e-6f);
}

// ---------------- bf16 MFMA GEMM, 128x128 tile (m97 structure) ----------------
// C[m,n] = act(sum_k A[m,k]*Bt[n,k] + bias) (+resid). BK=64, 4 waves (2x2),
// each wave 64x64 = 4x4 16x16 frags. LDS XOR-swizzle (linear dest, pre-swizzled
// global source, swizzled read).
// BIASMODE: 0 none, 1 per-n, 2 per-m. ACT: 0 none, 1 relu, 2 gelu, 3 *SCALE_Q.
// OUTMODE: 0 fp32, 1 bf16,
//          3 fused QKV split (Cout=q *SCALE_Q, D1=k, D2=v transposed /1024),
//          4 fused KV split (Cout=k2, D2=v2 transposed /512).
template <int BIASMODE, int ACT, bool RESID, int OUTMODE>
__global__ __launch_bounds__(256) void bgemm_kernel(
    const u16* __restrict__ A, const u16* __restrict__ Bt,
    const float* __restrict__ bias, const float* __restrict__ Rres,
    void* __restrict__ Cout, int M, int N, int K,
    long sA, long sB, long sC,
    u16* __restrict__ D1, u16* __restrict__ D2,
    const float* __restrict__ bias1, const float* __restrict__ bias2) {
    A  += (long)blockIdx.z * sA;
    Bt += (long)blockIdx.z * sB;
    __shared__ u16 As[128 * 64];
    __shared__ u16 Bs[128 * 64];
    int tid = threadIdx.x;
    int lane = tid & 63, wv = tid >> 6;
    int wr = wv >> 1, wc = wv & 1;
    int m0 = blockIdx.x * 128, n0 = blockIdx.y * 128;
    f32x4 acc[4][4] = {};
    int srow = lane >> 3;                       // row-within-8
    int selem = (((lane & 7) ^ srow) << 3);     // pre-swizzled source elem offset
    for (int k0 = 0; k0 < K; k0 += 64) {
        #pragma unroll
        for (int p = 0; p < 4; p++) {
            int r = p * 32 + wv * 8 + srow;
            gload_lds16(A + (long)(m0 + r) * K + k0 + selem,
                        (char*)As + (p * 32 + wv * 8) * 128);
            gload_lds16(Bt + (long)(n0 + r) * K + k0 + selem,
                        (char*)Bs + (p * 32 + wv * 8) * 128);
        }
        __syncthreads();
        #pragma unroll
        for (int ks = 0; ks < 2; ks++) {
            bshort8 af[4], bf[4];
            int kbo = ks * 64 + ((lane >> 4) << 4);
            #pragma unroll
            for (int f = 0; f < 4; f++) {
                int arow = wr * 64 + f * 16 + (lane & 15);
                af[f] = *(const bshort8*)((const char*)As + arow * 128 +
                                          (kbo ^ ((arow & 7) << 4)));
                int brow = wc * 64 + f * 16 + (lane & 15);
                bf[f] = *(const bshort8*)((const char*)Bs + brow * 128 +
                                          (kbo ^ ((brow & 7) << 4)));
            }
            #pragma unroll
            for (int fi = 0; fi < 4; fi++)
                #pragma unroll
                for (int fj = 0; fj < 4; fj++)
                    acc[fi][fj] = __builtin_amdgcn_mfma_f32_16x16x32_bf16(
                        af[fi], bf[fj], acc[fi][fj], 0, 0, 0);
        }
        __syncthreads();
    }
    #pragma unroll
    for (int fi = 0; fi < 4; fi++)
        #pragma unroll
        for (int fj = 0; fj < 4; fj++)
            #pragma unroll
            for (int r = 0; r < 4; r++) {
                int row = m0 + wr * 64 + fi * 16 + ((lane >> 4) << 2) + r;
                int col = n0 + wc * 64 + fj * 16 + (lane & 15);
                float v = acc[fi][fj][r];
                if (OUTMODE == 3) {
                    int grp = col >> 9, c = col & 511;
                    float bb = (grp == 0) ? bias[c] : (grp == 1) ? bias1[c] : bias2[c];
                    float vv = v + bb;
                    if (grp == 0)
                        ((u16*)Cout)[(long)row * 512 + c] = f2b(vv * SCALE_Q);
                    else if (grp == 1)
                        D1[(long)row * 512 + c] = f2b(vv);
                    else
                        D2[((long)((row >> 10) * 512 + c) << 10) + (row & 1023)] = f2b(vv);
                } else if (OUTMODE == 4) {
                    int grp = col >> 9, c = col & 511;
                    float vv = v + ((grp == 0) ? bias[c] : bias1[c]);
                    if (grp == 0)
                        ((u16*)Cout)[(long)row * 512 + c] = f2b(vv);
                    else
                        D2[((long)((row >> 9) * 512 + c) << 9) + (row & 511)] = f2b(vv);
                } else {
                    if (BIASMODE == 1) v += bias[col];
                    if (BIASMODE == 2) v += bias[row];
                    if (ACT == 1) v = fmaxf(v, 0.f);
                    if (ACT == 2) v = 0.5f * v * (1.f + erff(v * 0.70710678118654752f));
                    if (ACT == 3) v *= SCALE_Q;
                    if (RESID) v += Rres[(long)row * N + col];
                    long off = (long)blockIdx.z * sC + (long)row * N + col;
                    if (OUTMODE == 1) ((u16*)Cout)[off] = f2b(v);
                    else              ((float*)Cout)[off] = v;
                }
            }
}

// ---------------- fused MFMA flash attention: 8 waves, S-split, no-max exp2 ---------
// Q [B,L,512] bf16 (pre-scaled), K [B,S,512] bf16, Vt [B,512,S] bf16.
// Grid (bh=64, L/128, 2 S-chunks), 512 threads; block = 128 queries x half the keys.
// Waves 0-3 stage the K tile (64 keys x 32d, 64B rows, chunk^=(row>>1)&3 swizzle),
// waves 4-7 stage V^T (32d x 64 keys, 128B rows, chunk^=(row&7)). Double-buffered,
// one gload/thread/tile, counted s_waitcnt vmcnt(1). Unnormalized partials out
// (summable across S-chunks since softmax is unshifted): Pacc f32 + Pml sums.
__global__ __launch_bounds__(512) void attn_mfma_kernel(
    const u16* __restrict__ Q, const u16* __restrict__ K,
    const u16* __restrict__ Vt, float* __restrict__ Pacc0,
    float* __restrict__ Pacc1, float* __restrict__ Pml, int L, int S) {
    __shared__ __align__(16) u16 Ks[2][2048];
    __shared__ __align__(16) u16 Vs[2][2048];
    int bh = blockIdx.x;
    int b = bh >> 4, h = bh & 15;
    int z = blockIdx.z;
    int tid = threadIdx.x;
    int lane = tid & 63, wv = tid >> 6;
    int q0 = blockIdx.y * 128 + wv * 16;
    int qr = lane & 15, g = lane >> 4, g8 = g * 8;
    int kperm = 8 * (qr >> 2) + (qr & 3);
    int sbeg = z * (S >> 1);
    int nt = S >> 7;  // tiles of 64 keys in this half

    const u16* Kb = K + (long)b * S * 512 + h * 32;
    const u16* Vb = Vt + ((long)b * 512 + h * 32) * S;
    bshort8 qf = *(const bshort8*)(Q + ((long)(b * L + q0 + qr)) * 512 + h * 32 + g8);

    // staging sources (pre-swizzled) and LDS dests
    const u16* src;
    long step;
    char *d0, *d1;
    if (wv < 4) {
        int rk = wv * 16 + (lane >> 2);
        int sc = (lane & 3) ^ ((lane >> 3) & 3);  // (rk>>1)&3 == (lane>>3)&3
        src = Kb + (long)(sbeg + rk) * 512 + sc * 8;
        step = (long)64 * 512;
        d0 = (char*)Ks[0] + wv * 1024;
        d1 = (char*)Ks[1] + wv * 1024;
    } else {
        int rv = (wv - 4) * 8 + (lane >> 3);
        int sc = (lane & 7) ^ (lane >> 3);        // rv&7 == lane>>3
        src = Vb + (long)rv * S + sbeg + sc * 8;
        step = 64;
        d0 = (char*)Vs[0] + (wv - 4) * 1024;
        d1 = (char*)Vs[1] + (wv - 4) * 1024;
    }

    f32x4 acc0 = {}, acc1 = {};
    float lsum = 0.f;

    gload_lds16(src, d0);
    int cur = 0;
    for (int t = 0; t < nt; ++t) {
        if (t + 1 < nt) {
            gload_lds16(src + (long)(t + 1) * step, cur ? d0 : d1);
            asm volatile("s_waitcnt vmcnt(1)\ns_barrier" ::: "memory");
        } else {
            asm volatile("s_waitcnt vmcnt(0)\ns_barrier" ::: "memory");
        }
        const char* Kt = (const char*)Ks[cur];
        const char* Vl = (const char*)Vs[cur];
        bshort8 a0 = *(const bshort8*)(Kt + kperm * 64 + ((g ^ ((kperm >> 1) & 3)) << 4));
        bshort8 a1 = *(const bshort8*)(Kt + (kperm + 4) * 64 + ((g ^ (((kperm + 4) >> 1) & 3)) << 4));
        bshort8 a2 = *(const bshort8*)(Kt + (kperm + 32) * 64 + ((g ^ (((kperm + 32) >> 1) & 3)) << 4));
        bshort8 a3 = *(const bshort8*)(Kt + (kperm + 36) * 64 + ((g ^ (((kperm + 36) >> 1) & 3)) << 4));
        bshort8 v00 = *(const bshort8*)(Vl + qr * 128 + ((g ^ (qr & 7)) << 4));
        bshort8 v01 = *(const bshort8*)(Vl + qr * 128 + (((g + 4) ^ (qr & 7)) << 4));
        bshort8 v10 = *(const bshort8*)(Vl + (16 + qr) * 128 + ((g ^ (qr & 7)) << 4));
        bshort8 v11 = *(const bshort8*)(Vl + (16 + qr) * 128 + (((g + 4) ^ (qr & 7)) << 4));
        f32x4 zz = {0.f, 0.f, 0.f, 0.f};
        f32x4 st0 = __builtin_amdgcn_mfma_f32_16x16x32_bf16(a0, qf, zz, 0, 0, 0);
        f32x4 st1 = __builtin_amdgcn_mfma_f32_16x16x32_bf16(a1, qf, zz, 0, 0, 0);
        f32x4 st2 = __builtin_amdgcn_mfma_f32_16x16x32_bf16(a2, qf, zz, 0, 0, 0);
        f32x4 st3 = __builtin_amdgcn_mfma_f32_16x16x32_bf16(a3, qf, zz, 0, 0, 0);
        float p0[4], p1[4], p2[4], p3[4];
        #pragma unroll
        for (int r = 0; r < 4; r++) {
            p0[r] = exp2c(st0[r]);
            p1[r] = exp2c(st1[r]);
            p2[r] = exp2c(st2[r]);
            p3[r] = exp2c(st3[r]);
        }
        float ps = ((p0[0] + p0[1]) + (p0[2] + p0[3])) + ((p1[0] + p1[1]) + (p1[2] + p1[3])) +
                   ((p2[0] + p2[1]) + (p2[2] + p2[3])) + ((p3[0] + p3[1]) + (p3[2] + p3[3]));
        lsum += ps;
        u32x4 P0 = { cvtpk(p0[0], p0[1]), cvtpk(p0[2], p0[3]),
                     cvtpk(p1[0], p1[1]), cvtpk(p1[2], p1[3]) };
        u32x4 P1 = { cvtpk(p2[0], p2[1]), cvtpk(p2[2], p2[3]),
                     cvtpk(p3[0], p3[1]), cvtpk(p3[2], p3[3]) };
        bshort8 pf0 = *(bshort8*)&P0;
        bshort8 pf1 = *(bshort8*)&P1;
        acc0 = __builtin_amdgcn_mfma_f32_16x16x32_bf16(v00, pf0, acc0, 0, 0, 0);
        acc0 = __builtin_amdgcn_mfma_f32_16x16x32_bf16(v01, pf1, acc0, 0, 0, 0);
        acc1 = __builtin_amdgcn_mfma_f32_16x16x32_bf16(v10, pf0, acc1, 0, 0, 0);
        acc1 = __builtin_amdgcn_mfma_f32_16x16x32_bf16(v11, pf1, acc1, 0, 0, 0);
        asm volatile("s_barrier" ::: "memory");
        cur ^= 1;
    }

    lsum += __shfl_xor(lsum, 16);
    lsum += __shfl_xor(lsum, 32);
    float* PZ = z ? Pacc1 : Pacc0;
    float* pa = PZ + (((long)b * L + q0 + qr) << 9) + h * 32 + g * 4;
    *(f32x4*)pa = acc0;
    *(f32x4*)(pa + 16) = acc1;
    if (g == 0) Pml[(long)z * 65536 + (long)bh * L + q0 + qr] = lsum;
}

// ---------------- attention combine: O = (P0+P1)/(l0+l1) -> bf16 ----------------
__global__ __launch_bounds__(256) void attn_combine_kernel(
    const float* __restrict__ P0, const float* __restrict__ P1,
    const float* __restrict__ Pml, u16* __restrict__ O) {
    long e = ((long)blockIdx.x * 256 + threadIdx.x) * 8;  // over 4096x512 f32
    int q = (int)(e >> 9);
    int c = (int)(e & 511);
    int h = c >> 5;
    int b = q >> 10, l = q & 1023;
    int bh = b * 16 + h;
    float l0 = Pml[bh * 1024 + l];
    float l1 = Pml[65536 + bh * 1024 + l];
    float inv = 1.f / (l0 + l1);
    f32x4 x0 = *(const f32x4*)(P0 + e);
    f32x4 x1 = *(const f32x4*)(P0 + e + 4);
    f32x4 y0 = *(const f32x4*)(P1 + e);
    f32x4 y1 = *(const f32x4*)(P1 + e + 4);
    sshort4 o0, o1;
    #pragma unroll
    for (int r = 0; r < 4; r++) {
        o0[r] = (short)f2b((x0[r] + y0[r]) * inv);
        o1[r] = (short)f2b((x1[r] + y1[r]) * inv);
    }
    *(sshort4*)(O + e) = o0;
    *(sshort4*)(O + e + 4) = o1;
}

// ---------------- layernorm over 512; optional bf16 dual-store / transposed out ------
template <bool TRANS, bool DUAL>
__global__ __launch_bounds__(256) void ln_kernel(const float* __restrict__ X,
                                                 const float* __restrict__ g,
                                                 const float* __restrict__ bt,
                                                 float* __restrict__ Y,
                                                 u16* __restrict__ Yb) {
    int row = blockIdx.x;
    const float* xr = X + (long)row * 512;
    int t = threadIdx.x;
    float x0 = xr[t], x1 = xr[t + 256];
    float s = x0 + x1, ss = x0 * x0 + x1 * x1;
    #pragma unroll
    for (int off = 32; off > 0; off >>= 1) {
        s += __shfl_down(s, off);
        ss += __shfl_down(ss, off);
    }
    __shared__ float sred[4], ssred[4];
    int wid = t >> 6;
    if ((t & 63) == 0) { sred[wid] = s; ssred[wid] = ss; }
    __syncthreads();
    float ts = sred[0] + sred[1] + sred[2] + sred[3];
    float tss = ssred[0] + ssred[1] + ssred[2] + ssred[3];
    float mean = ts * (1.f / 512.f);
    float var = tss * (1.f / 512.f) - mean * mean;
    float rstd = rsqrtf(var + 1e-5f);
    float y0 = (x0 - mean) * rstd * g[t] + bt[t];
    float y1 = (x1 - mean) * rstd * g[t + 256] + bt[t + 256];
    if (TRANS) {
        int b = row >> 10, l = row & 1023;
        Y[((long)b * 512 + t) * 1024 + l] = y0;
        Y[((long)b * 512 + t + 256) * 1024 + l] = y1;
    } else {
        Y[(long)row * 512 + t] = y0;
        Y[(long)row * 512 + t + 256] = y1;
    }
    if (DUAL) {
        Yb[(long)row * 512 + t] = f2b(y0);
        Yb[(long)row * 512 + t + 256] = f2b(y1);
    }
}

extern "C" void kernel_launch(void* const* d_in, const int* in_sizes, int n_in,
                              void* d_out, int out_size, void* d_ws, size_t ws_size,
                              hipStream_t stream) {
    const float* x      = (const float*)d_in[0];
    const float* gfeat  = (const float*)d_in[1];
    const float* conv_w = (const float*)d_in[2];
    const float* conv_b = (const float*)d_in[3];
    const float* sa_wq = (const float*)d_in[4];
    const float* sa_bq = (const float*)d_in[5];
    const float* sa_wk = (const float*)d_in[6];
    const float* sa_bk = (const float*)d_in[7];
    const float* sa_wv = (const float*)d_in[8];
    const float* sa_bv = (const float*)d_in[9];
    const float* sa_wo = (const float*)d_in[10];
    const float* sa_bo = (const float*)d_in[11];
    const float* ca_wq = (const float*)d_in[12];
    const float* ca_bq = (const float*)d_in[13];
    const float* ca_wk = (const float*)d_in[14];
    const float* ca_bk = (const float*)d_in[15];
    const float* ca_wv = (const float*)d_in[16];
    const float* ca_bv = (const float*)d_in[17];
    const float* ca_wo = (const float*)d_in[18];
    const float* ca_bo = (const float*)d_in[19];
    const float* ffn_w1 = (const float*)d_in[20];
    const float* ffn_b1 = (const float*)d_in[21];
    const float* ffn_w2 = (const float*)d_in[22];
    const float* ffn_b2 = (const float*)d_in[23];
    const float* n1_g = (const float*)d_in[24];
    const float* n1_b = (const float*)d_in[25];
    const float* n2_g = (const float*)d_in[26];
    const float* n2_b = (const float*)d_in[27];
    const float* n3_g = (const float*)d_in[28];
    const float* n3_b = (const float*)d_in[29];
    (void)ws_size; (void)n_in; (void)in_sizes; (void)out_size;

    const long M_ = 1048576;
    float* W0 = (float*)d_ws;
    float* h   = W0;                 // [0, 2M) fp32
    float* hn  = W0 + 2 * M_;        // [2M, 4M) fp32
    u16* U = (u16*)(W0 + 4 * M_);
    u16* qb     = U;                 // 2M u16
    u16* kb     = U + 2 * M_;        // 2M
    u16* vtb    = U + 4 * M_;        // 2M   [4][512][1024]
    u16* k2b    = U + 6 * M_;        // 1M
    u16* v2tb   = U + 7 * M_;        // 1M   [4][512][512]
    u16* attb   = U + 8 * M_;        // 2M
    u16* hnb    = U + 10 * M_;       // 2M
    u16* midb   = U + 12 * M_;       // 8M
    u16* wsb    = U + 20 * M_;       // 6.55M
    u16* res_tb = U + 27 * M_;       // 1M
    u16* crossb = U + 28 * M_;       // 1M

    // attention partial overlays (regions dead at those pipeline points):
    float* sP0 = h;                          // self z=0: 8MB
    float* sP1 = hn;                         // self z=1: 8MB
    float* sPml = (float*)midb;              // 512KB
    float* cP0 = (float*)(U + 2 * M_);       // cross z=0: kb+vtb (dead)
    float* cP1 = (float*)(U + 12 * M_);      // cross z=1: midb first half
    float* cPml = (float*)(U + 16 * M_);     // midb second half

    const u16* conv_wb = wsb;
    const u16* sa_wqb = wsb + 262144;   // wq,wk,wv contiguous -> fused QKV weight
    const u16* sa_wob = wsb + 1048576;
    const u16* ca_wqb = wsb + 1310720;
    const u16* ca_wkb = wsb + 1572864;  // wk,wv contiguous -> fused KV weight
    const u16* ca_wob = wsb + 2097152;
    const u16* ffn1b = wsb + 2359296, *ffn2b = wsb + 3407872;
    const u16* xb = wsb + 4456448;

    // 0. convert weights + x to bf16
    WSrc ws;
    ws.p[0] = conv_w; ws.p[1] = sa_wq; ws.p[2] = sa_wk; ws.p[3] = sa_wv;
    ws.p[4] = sa_wo; ws.p[5] = ca_wq; ws.p[6] = ca_wk; ws.p[7] = ca_wv;
    ws.p[8] = ca_wo; ws.p[9] = ffn_w1; ws.p[10] = ffn_w2; ws.p[11] = x;
    wconv_kernel<<<6400, 256, 0, stream>>>(ws, wsb);

    // 1. window |max-min|+eps, transposed bf16: res_tb [b][n][c]
    win_kernel<<<4096, 256, 0, stream>>>(gfeat, res_tb, 4 * 512 * 512);

    // 2. conv+relu: crossb[b][o][n]   (M=512 per batch, 128-tile grid 4x4x4)
    bgemm_kernel<2, 1, false, 1><<<dim3(4, 4, 4), 256, 0, stream>>>(
        conv_wb, res_tb, conv_b, nullptr, crossb, 512, 512, 512, 0, 262144, 262144,
        nullptr, nullptr, nullptr, nullptr);

    // 3. fused self-attn QKV projection: N=1536 -> qb (scaled), kb, vtb (transposed)
    bgemm_kernel<1, 0, false, 3><<<dim3(32, 12), 256, 0, stream>>>(
        xb, sa_wqb, sa_bq, nullptr, qb, 4096, 1536, 512, 0, 0, 0,
        kb, vtb, sa_bk, sa_bv);

    // 4. self attention (S=1024): 2 S-chunks of summable partials + combine
    attn_mfma_kernel<<<dim3(64, 8, 2), 512, 0, stream>>>(
        qb, kb, vtb, sP0, sP1, sPml, 1024, 1024);
    attn_combine_kernel<<<1024, 256, 0, stream>>>(sP0, sP1, sPml, attb);

    // 5. out proj + resid x -> h fp32
    bgemm_kernel<1, 0, true, 0><<<dim3(32, 4), 256, 0, stream>>>(
        attb, sa_wob, sa_bo, x, h, 4096, 512, 512, 0, 0, 0,
        nullptr, nullptr, nullptr, nullptr);

    // 6. LN1 -> hn fp32 + hnb bf16
    ln_kernel<false, true><<<4096, 256, 0, stream>>>(h, n1_g, n1_b, hn, hnb);

    // 7. cross-attn: Q proj (scaled), fused K2/V2 proj
    bgemm_kernel<1, 3, false, 1><<<dim3(32, 4), 256, 0, stream>>>(
        hnb, ca_wqb, ca_bq, nullptr, qb, 4096, 512, 512, 0, 0, 0,
        nullptr, nullptr, nullptr, nullptr);
    bgemm_kernel<1, 0, false, 4><<<dim3(16, 8), 256, 0, stream>>>(
        crossb, ca_wkb, ca_bk, nullptr, k2b, 2048, 1024, 512, 0, 0, 0,
        nullptr, v2tb, ca_bv, nullptr);

    // 8. cross attention (S=512): 2 S-chunks + combine
    attn_mfma_kernel<<<dim3(64, 8, 2), 512, 0, stream>>>(
        qb, k2b, v2tb, cP0, cP1, cPml, 1024, 512);
    attn_combine_kernel<<<1024, 256, 0, stream>>>(cP0, cP1, cPml, attb);

    // 9. out proj + resid hn -> h fp32
    bgemm_kernel<1, 0, true, 0><<<dim3(32, 4), 256, 0, stream>>>(
        attb, ca_wob, ca_bo, hn, h, 4096, 512, 512, 0, 0, 0,
        nullptr, nullptr, nullptr, nullptr);

    // 10. LN2 -> hn fp32 + hnb bf16
    ln_kernel<false, true><<<4096, 256, 0, stream>>>(h, n2_g, n2_b, hn, hnb);

    // 11. FFN up + exact gelu -> midb bf16  [4096,2048]
    bgemm_kernel<1, 2, false, 1><<<dim3(32, 16), 256, 0, stream>>>(
        hnb, ffn1b, ffn_b1, nullptr, midb, 4096, 2048, 512, 0, 0, 0,
        nullptr, nullptr, nullptr, nullptr);

    // 12. FFN down + resid hn -> h fp32  [4096,512] K=2048
    bgemm_kernel<1, 0, true, 0><<<dim3(32, 4), 256, 0, stream>>>(
        midb, ffn2b, ffn_b2, hn, h, 4096, 512, 2048, 0, 0, 0,
        nullptr, nullptr, nullptr, nullptr);

    // 13. LN3 + transpose -> d_out [B,512,L] fp32
    ln_kernel<true, false><<<4096, 256, 0, stream>>>(h, n3_g, n3_b, (float*)d_out, nullptr);
}

// Round 8
// 205.253 us; speedup vs baseline: 1.2108x; 1.2108x over previous
//
#include <hip/hip_runtime.h>
#include <hip/hip_bf16.h>
#include <math.h>

#define SCALE_Q 0.25504522f  // 1/sqrt(32) * log2(e)  (Q pre-scale for exp2 softmax)

typedef unsigned short u16;
typedef unsigned int u32;
typedef __attribute__((ext_vector_type(8))) short bshort8;
typedef __attribute__((ext_vector_type(4))) short sshort4;
typedef __attribute__((ext_vector_type(4))) float f32x4;
typedef __attribute__((ext_vector_type(4))) u32 u32x4;

__device__ inline u16 f2b(float f) {  // fp32 -> bf16 RNE
    union { float f; uint32_t u; } c;
    c.f = f;
    uint32_t u = c.u;
    return (u16)((u + 0x7fffu + ((u >> 16) & 1u)) >> 16);
}

__device__ __forceinline__ u32 cvtpk(float a, float b) {  // {lo=bf16(a), hi=bf16(b)}
    u32 r;
    asm("v_cvt_pk_bf16_f32 %0, %1, %2" : "=v"(r) : "v"(a), "v"(b));
    return r;
}

__device__ __forceinline__ float exp2c(float s) {  // 2^min(s,100)
    float c = fminf(s, 100.f);
    float r;
    asm("v_exp_f32 %0, %1" : "=v"(r) : "v"(c));
    return r;
}

__device__ inline void gload_lds16(const void* g, void* lds) {
    __builtin_amdgcn_global_load_lds(
        (const __attribute__((address_space(1))) void*)g,
        (__attribute__((address_space(3))) void*)lds, 16, 0, 0);
}

// ---------------- batched fp32->bf16 convert (11 weights + x) ----------------
struct WSrc { const float* p[12]; };
__global__ __launch_bounds__(256) void wconv_kernel(WSrc s, u16* __restrict__ dst) {
    long e = ((long)blockIdx.x * 256 + threadIdx.x) * 4;
    if (e >= 6553600) return;
    int w; long base;
    if (e < 2359296)      { w = (int)(e >> 18); base = (long)w << 18; }
    else if (e < 3407872) { w = 9;  base = 2359296; }
    else if (e < 4456448) { w = 10; base = 3407872; }
    else                  { w = 11; base = 4456448; }
    float4 v = *(const float4*)(s.p[w] + (e - base));
    dst[e + 0] = f2b(v.x); dst[e + 1] = f2b(v.y);
    dst[e + 2] = f2b(v.z); dst[e + 3] = f2b(v.w);
}

// ---------------- window |max-min| + eps -> transposed bf16 [b][n][c] ----------------
__global__ __launch_bounds__(256) void win_kernel(const float* __restrict__ G,
                                                  u16* __restrict__ Rt, int total) {
    int i = blockIdx.x * 256 + threadIdx.x;
    if (i >= total) return;
    const float4* p = reinterpret_cast<const float4*>(G) + (size_t)i * 2;
    float4 a = p[0], b = p[1];
    float mx = fmaxf(fmaxf(fmaxf(a.x, a.y), fmaxf(a.z, a.w)),
                     fmaxf(fmaxf(b.x, b.y), fmaxf(b.z, b.w)));
    float mn = fminf(fminf(fminf(a.x, a.y), fminf(a.z, a.w)),
                     fminf(fminf(b.x, b.y), fminf(b.z, b.w)));
    int b_ = i >> 18, c = (i >> 9) & 511, n = i & 511;
    Rt[((long)(b_ * 512 + n) << 9) + c] = f2b(fabsf(mx - mn) + 1e-6f);
}

// ================= shared epilogue =================
template <int BIASMODE, int ACT, bool RESID, int OUTMODE>
__device__ __forceinline__ void gemm_epilogue_elem(
    float v, int row, int col, int N, long zoff,
    const float* bias, const float* Rres, void* Cout,
    u16* D1, u16* D2, const float* bias1, const float* bias2) {
    if (OUTMODE == 3) {  // fused QKV split
        int grp = col >> 9, c = col & 511;
        float bb = (grp == 0) ? bias[c] : (grp == 1) ? bias1[c] : bias2[c];
        float vv = v + bb;
        if (grp == 0)
            ((u16*)Cout)[(long)row * 512 + c] = f2b(vv * SCALE_Q);
        else if (grp == 1)
            D1[(long)row * 512 + c] = f2b(vv);
        else
            D2[((long)((row >> 10) * 512 + c) << 10) + (row & 1023)] = f2b(vv);
    } else if (OUTMODE == 4) {  // fused KV split
        int grp = col >> 9, c = col & 511;
        float vv = v + ((grp == 0) ? bias[c] : bias1[c]);
        if (grp == 0)
            ((u16*)Cout)[(long)row * 512 + c] = f2b(vv);
        else
            D2[((long)((row >> 9) * 512 + c) << 9) + (row & 511)] = f2b(vv);
    } else {
        if (BIASMODE == 1) v += bias[col];
        if (BIASMODE == 2) v += bias[row];
        if (ACT == 1) v = fmaxf(v, 0.f);
        if (ACT == 2) v = 0.5f * v * (1.f + erff(v * 0.70710678118654752f));
        if (ACT == 3) v *= SCALE_Q;
        if (RESID) v += Rres[(long)row * N + col];
        long off = zoff + (long)row * N + col;
        if (OUTMODE == 1) ((u16*)Cout)[off] = f2b(v);
        else              ((float*)Cout)[off] = v;
    }
}

// ---------------- bf16 MFMA GEMM, 64x64 tile (for N=512-class shapes) ----------------
template <int BIASMODE, int ACT, bool RESID, int OUTMODE>
__global__ __launch_bounds__(256) void bgemm64_kernel(
    const u16* __restrict__ A, const u16* __restrict__ Bt,
    const float* __restrict__ bias, const float* __restrict__ Rres,
    void* __restrict__ Cout, int M, int N, int K,
    long sA, long sB, long sC,
    u16* __restrict__ D1, u16* __restrict__ D2,
    const float* __restrict__ bias1, const float* __restrict__ bias2) {
    A  += (long)blockIdx.z * sA;
    Bt += (long)blockIdx.z * sB;
    __shared__ u16 As[64 * 64];
    __shared__ u16 Bs[64 * 64];
    int tid = threadIdx.x;
    int lane = tid & 63, wv = tid >> 6;
    int wr = wv >> 1, wc = wv & 1;
    int m0 = blockIdx.x * 64, n0 = blockIdx.y * 64;
    f32x4 acc[2][2] = {};
    int srow = lane >> 3;
    int selem = ((lane & 7) ^ srow) << 3;
    for (int k0 = 0; k0 < K; k0 += 64) {
        #pragma unroll
        for (int i = 0; i < 2; i++) {
            int roff = i * 32 + wv * 8;
            gload_lds16(A + (long)(m0 + roff + srow) * K + k0 + selem,
                        (char*)As + roff * 128);
            gload_lds16(Bt + (long)(n0 + roff + srow) * K + k0 + selem,
                        (char*)Bs + roff * 128);
        }
        __syncthreads();
        #pragma unroll
        for (int ks = 0; ks < 2; ks++) {
            bshort8 af[2], bf[2];
            int kbo = ks * 64 + ((lane >> 4) << 4);
            #pragma unroll
            for (int f = 0; f < 2; f++) {
                int arow = wr * 32 + f * 16 + (lane & 15);
                af[f] = *(const bshort8*)((const char*)As + arow * 128 +
                                          (kbo ^ ((arow & 7) << 4)));
                int brow = wc * 32 + f * 16 + (lane & 15);
                bf[f] = *(const bshort8*)((const char*)Bs + brow * 128 +
                                          (kbo ^ ((brow & 7) << 4)));
            }
            #pragma unroll
            for (int fi = 0; fi < 2; fi++)
                #pragma unroll
                for (int fj = 0; fj < 2; fj++)
                    acc[fi][fj] = __builtin_amdgcn_mfma_f32_16x16x32_bf16(
                        af[fi], bf[fj], acc[fi][fj], 0, 0, 0);
        }
        __syncthreads();
    }
    long zoff = (long)blockIdx.z * sC;
    #pragma unroll
    for (int fi = 0; fi < 2; fi++)
        #pragma unroll
        for (int fj = 0; fj < 2; fj++)
            #pragma unroll
            for (int r = 0; r < 4; r++) {
                int row = m0 + wr * 32 + fi * 16 + ((lane >> 4) << 2) + r;
                int col = n0 + wc * 32 + fj * 16 + (lane & 15);
                gemm_epilogue_elem<BIASMODE, ACT, RESID, OUTMODE>(
                    acc[fi][fj][r], row, col, N, zoff, bias, Rres, Cout,
                    D1, D2, bias1, bias2);
            }
}

// ---------------- bf16 MFMA GEMM, 128x128 tile (for large-grid shapes) ----------------
template <int BIASMODE, int ACT, bool RESID, int OUTMODE>
__global__ __launch_bounds__(256) void bgemm128_kernel(
    const u16* __restrict__ A, const u16* __restrict__ Bt,
    const float* __restrict__ bias, const float* __restrict__ Rres,
    void* __restrict__ Cout, int M, int N, int K,
    long sA, long sB, long sC,
    u16* __restrict__ D1, u16* __restrict__ D2,
    const float* __restrict__ bias1, const float* __restrict__ bias2) {
    A  += (long)blockIdx.z * sA;
    Bt += (long)blockIdx.z * sB;
    __shared__ u16 As[128 * 64];
    __shared__ u16 Bs[128 * 64];
    int tid = threadIdx.x;
    int lane = tid & 63, wv = tid >> 6;
    int wr = wv >> 1, wc = wv & 1;
    int m0 = blockIdx.x * 128, n0 = blockIdx.y * 128;
    f32x4 acc[4][4] = {};
    int srow = lane >> 3;
    int selem = ((lane & 7) ^ srow) << 3;
    for (int k0 = 0; k0 < K; k0 += 64) {
        #pragma unroll
        for (int p = 0; p < 4; p++) {
            int roff = p * 32 + wv * 8;
            gload_lds16(A + (long)(m0 + roff + srow) * K + k0 + selem,
                        (char*)As + roff * 128);
            gload_lds16(Bt + (long)(n0 + roff + srow) * K + k0 + selem,
                        (char*)Bs + roff * 128);
        }
        __syncthreads();
        #pragma unroll
        for (int ks = 0; ks < 2; ks++) {
            bshort8 af[4], bf[4];
            int kbo = ks * 64 + ((lane >> 4) << 4);
            #pragma unroll
            for (int f = 0; f < 4; f++) {
                int arow = wr * 64 + f * 16 + (lane & 15);
                af[f] = *(const bshort8*)((const char*)As + arow * 128 +
                                          (kbo ^ ((arow & 7) << 4)));
                int brow = wc * 64 + f * 16 + (lane & 15);
                bf[f] = *(const bshort8*)((const char*)Bs + brow * 128 +
                                          (kbo ^ ((brow & 7) << 4)));
            }
            #pragma unroll
            for (int fi = 0; fi < 4; fi++)
                #pragma unroll
                for (int fj = 0; fj < 4; fj++)
                    acc[fi][fj] = __builtin_amdgcn_mfma_f32_16x16x32_bf16(
                        af[fi], bf[fj], acc[fi][fj], 0, 0, 0);
        }
        __syncthreads();
    }
    long zoff = (long)blockIdx.z * sC;
    #pragma unroll
    for (int fi = 0; fi < 4; fi++)
        #pragma unroll
        for (int fj = 0; fj < 4; fj++)
            #pragma unroll
            for (int r = 0; r < 4; r++) {
                int row = m0 + wr * 64 + fi * 16 + ((lane >> 4) << 2) + r;
                int col = n0 + wc * 64 + fj * 16 + (lane & 15);
                gemm_epilogue_elem<BIASMODE, ACT, RESID, OUTMODE>(
                    acc[fi][fj][r], row, col, N, zoff, bias, Rres, Cout,
                    D1, D2, bias1, bias2);
            }
}

// ---------------- fused MFMA flash attention: 8 waves, S-split, no-max exp2 ---------
__global__ __launch_bounds__(512) void attn_mfma_kernel(
    const u16* __restrict__ Q, const u16* __restrict__ K,
    const u16* __restrict__ Vt, float* __restrict__ Pacc0,
    float* __restrict__ Pacc1, float* __restrict__ Pml, int L, int S) {
    __shared__ __align__(16) u16 Ks[2][2048];
    __shared__ __align__(16) u16 Vs[2][2048];
    int bh = blockIdx.x;
    int b = bh >> 4, h = bh & 15;
    int z = blockIdx.z;
    int tid = threadIdx.x;
    int lane = tid & 63, wv = tid >> 6;
    int q0 = blockIdx.y * 128 + wv * 16;
    int qr = lane & 15, g = lane >> 4, g8 = g * 8;
    int kperm = 8 * (qr >> 2) + (qr & 3);
    int sbeg = z * (S >> 1);
    int nt = S >> 7;  // tiles of 64 keys in this half

    const u16* Kb = K + (long)b * S * 512 + h * 32;
    const u16* Vb = Vt + ((long)b * 512 + h * 32) * S;
    bshort8 qf = *(const bshort8*)(Q + ((long)(b * L + q0 + qr)) * 512 + h * 32 + g8);

    const u16* src;
    long step;
    char *d0, *d1;
    if (wv < 4) {
        int rk = wv * 16 + (lane >> 2);
        int sc = (lane & 3) ^ ((lane >> 3) & 3);
        src = Kb + (long)(sbeg + rk) * 512 + sc * 8;
        step = (long)64 * 512;
        d0 = (char*)Ks[0] + wv * 1024;
        d1 = (char*)Ks[1] + wv * 1024;
    } else {
        int rv = (wv - 4) * 8 + (lane >> 3);
        int sc = (lane & 7) ^ (lane >> 3);
        src = Vb + (long)rv * S + sbeg + sc * 8;
        step = 64;
        d0 = (char*)Vs[0] + (wv - 4) * 1024;
        d1 = (char*)Vs[1] + (wv - 4) * 1024;
    }

    f32x4 acc0 = {}, acc1 = {};
    float lsum = 0.f;

    gload_lds16(src, d0);
    int cur = 0;
    for (int t = 0; t < nt; ++t) {
        if (t + 1 < nt) {
            gload_lds16(src + (long)(t + 1) * step, cur ? d0 : d1);
            asm volatile("s_waitcnt vmcnt(1)\ns_barrier" ::: "memory");
        } else {
            asm volatile("s_waitcnt vmcnt(0)\ns_barrier" ::: "memory");
        }
        const char* Kt = (const char*)Ks[cur];
        const char* Vl = (const char*)Vs[cur];
        bshort8 a0 = *(const bshort8*)(Kt + kperm * 64 + ((g ^ ((kperm >> 1) & 3)) << 4));
        bshort8 a1 = *(const bshort8*)(Kt + (kperm + 4) * 64 + ((g ^ (((kperm + 4) >> 1) & 3)) << 4));
        bshort8 a2 = *(const bshort8*)(Kt + (kperm + 32) * 64 + ((g ^ (((kperm + 32) >> 1) & 3)) << 4));
        bshort8 a3 = *(const bshort8*)(Kt + (kperm + 36) * 64 + ((g ^ (((kperm + 36) >> 1) & 3)) << 4));
        bshort8 v00 = *(const bshort8*)(Vl + qr * 128 + ((g ^ (qr & 7)) << 4));
        bshort8 v01 = *(const bshort8*)(Vl + qr * 128 + (((g + 4) ^ (qr & 7)) << 4));
        bshort8 v10 = *(const bshort8*)(Vl + (16 + qr) * 128 + ((g ^ (qr & 7)) << 4));
        bshort8 v11 = *(const bshort8*)(Vl + (16 + qr) * 128 + (((g + 4) ^ (qr & 7)) << 4));
        f32x4 zz = {0.f, 0.f, 0.f, 0.f};
        f32x4 st0 = __builtin_amdgcn_mfma_f32_16x16x32_bf16(a0, qf, zz, 0, 0, 0);
        f32x4 st1 = __builtin_amdgcn_mfma_f32_16x16x32_bf16(a1, qf, zz, 0, 0, 0);
        f32x4 st2 = __builtin_amdgcn_mfma_f32_16x16x32_bf16(a2, qf, zz, 0, 0, 0);
        f32x4 st3 = __builtin_amdgcn_mfma_f32_16x16x32_bf16(a3, qf, zz, 0, 0, 0);
        float p0[4], p1[4], p2[4], p3[4];
        #pragma unroll
        for (int r = 0; r < 4; r++) {
            p0[r] = exp2c(st0[r]);
            p1[r] = exp2c(st1[r]);
            p2[r] = exp2c(st2[r]);
            p3[r] = exp2c(st3[r]);
        }
        float ps = ((p0[0] + p0[1]) + (p0[2] + p0[3])) + ((p1[0] + p1[1]) + (p1[2] + p1[3])) +
                   ((p2[0] + p2[1]) + (p2[2] + p2[3])) + ((p3[0] + p3[1]) + (p3[2] + p3[3]));
        lsum += ps;
        u32x4 P0 = { cvtpk(p0[0], p0[1]), cvtpk(p0[2], p0[3]),
                     cvtpk(p1[0], p1[1]), cvtpk(p1[2], p1[3]) };
        u32x4 P1 = { cvtpk(p2[0], p2[1]), cvtpk(p2[2], p2[3]),
                     cvtpk(p3[0], p3[1]), cvtpk(p3[2], p3[3]) };
        bshort8 pf0 = *(bshort8*)&P0;
        bshort8 pf1 = *(bshort8*)&P1;
        acc0 = __builtin_amdgcn_mfma_f32_16x16x32_bf16(v00, pf0, acc0, 0, 0, 0);
        acc0 = __builtin_amdgcn_mfma_f32_16x16x32_bf16(v01, pf1, acc0, 0, 0, 0);
        acc1 = __builtin_amdgcn_mfma_f32_16x16x32_bf16(v10, pf0, acc1, 0, 0, 0);
        acc1 = __builtin_amdgcn_mfma_f32_16x16x32_bf16(v11, pf1, acc1, 0, 0, 0);
        asm volatile("s_barrier" ::: "memory");
        cur ^= 1;
    }

    lsum += __shfl_xor(lsum, 16);
    lsum += __shfl_xor(lsum, 32);
    float* PZ = z ? Pacc1 : Pacc0;
    float* pa = PZ + (((long)b * L + q0 + qr) << 9) + h * 32 + g * 4;
    *(f32x4*)pa = acc0;
    *(f32x4*)(pa + 16) = acc1;
    if (g == 0) Pml[(long)z * 65536 + (long)bh * L + q0 + qr] = lsum;
}

// ---------------- attention combine: O = (P0+P1)/(l0+l1) -> bf16 ----------------
__global__ __launch_bounds__(256) void attn_combine_kernel(
    const float* __restrict__ P0, const float* __restrict__ P1,
    const float* __restrict__ Pml, u16* __restrict__ O) {
    long e = ((long)blockIdx.x * 256 + threadIdx.x) * 8;  // over 4096x512 f32
    int q = (int)(e >> 9);
    int c = (int)(e & 511);
    int h = c >> 5;
    int b = q >> 10, l = q & 1023;
    int bh = b * 16 + h;
    float l0 = Pml[bh * 1024 + l];
    float l1 = Pml[65536 + bh * 1024 + l];
    float inv = 1.f / (l0 + l1);
    f32x4 x0 = *(const f32x4*)(P0 + e);
    f32x4 x1 = *(const f32x4*)(P0 + e + 4);
    f32x4 y0 = *(const f32x4*)(P1 + e);
    f32x4 y1 = *(const f32x4*)(P1 + e + 4);
    sshort4 o0, o1;
    #pragma unroll
    for (int r = 0; r < 4; r++) {
        o0[r] = (short)f2b((x0[r] + y0[r]) * inv);
        o1[r] = (short)f2b((x1[r] + y1[r]) * inv);
    }
    *(sshort4*)(O + e) = o0;
    *(sshort4*)(O + e + 4) = o1;
}

// ---------------- layernorm over 512; optional bf16 dual-store / transposed out ------
template <bool TRANS, bool DUAL>
__global__ __launch_bounds__(256) void ln_kernel(const float* __restrict__ X,
                                                 const float* __restrict__ g,
                                                 const float* __restrict__ bt,
                                                 float* __restrict__ Y,
                                                 u16* __restrict__ Yb) {
    int row = blockIdx.x;
    const float* xr = X + (long)row * 512;
    int t = threadIdx.x;
    float x0 = xr[t], x1 = xr[t + 256];
    float s = x0 + x1, ss = x0 * x0 + x1 * x1;
    #pragma unroll
    for (int off = 32; off > 0; off >>= 1) {
        s += __shfl_down(s, off);
        ss += __shfl_down(ss, off);
    }
    __shared__ float sred[4], ssred[4];
    int wid = t >> 6;
    if ((t & 63) == 0) { sred[wid] = s; ssred[wid] = ss; }
    __syncthreads();
    float ts = sred[0] + sred[1] + sred[2] + sred[3];
    float tss = ssred[0] + ssred[1] + ssred[2] + ssred[3];
    float mean = ts * (1.f / 512.f);
    float var = tss * (1.f / 512.f) - mean * mean;
    float rstd = rsqrtf(var + 1e-5f);
    float y0 = (x0 - mean) * rstd * g[t] + bt[t];
    float y1 = (x1 - mean) * rstd * g[t + 256] + bt[t + 256];
    if (TRANS) {
        int b = row >> 10, l = row & 1023;
        Y[((long)b * 512 + t) * 1024 + l] = y0;
        Y[((long)b * 512 + t + 256) * 1024 + l] = y1;
    } else {
        Y[(long)row * 512 + t] = y0;
        Y[(long)row * 512 + t + 256] = y1;
    }
    if (DUAL) {
        Yb[(long)row * 512 + t] = f2b(y0);
        Yb[(long)row * 512 + t + 256] = f2b(y1);
    }
}

extern "C" void kernel_launch(void* const* d_in, const int* in_sizes, int n_in,
                              void* d_out, int out_size, void* d_ws, size_t ws_size,
                              hipStream_t stream) {
    const float* x      = (const float*)d_in[0];
    const float* gfeat  = (const float*)d_in[1];
    const float* conv_w = (const float*)d_in[2];
    const float* conv_b = (const float*)d_in[3];
    const float* sa_wq = (const float*)d_in[4];
    const float* sa_bq = (const float*)d_in[5];
    const float* sa_wk = (const float*)d_in[6];
    const float* sa_bk = (const float*)d_in[7];
    const float* sa_wv = (const float*)d_in[8];
    const float* sa_bv = (const float*)d_in[9];
    const float* sa_wo = (const float*)d_in[10];
    const float* sa_bo = (const float*)d_in[11];
    const float* ca_wq = (const float*)d_in[12];
    const float* ca_bq = (const float*)d_in[13];
    const float* ca_wk = (const float*)d_in[14];
    const float* ca_bk = (const float*)d_in[15];
    const float* ca_wv = (const float*)d_in[16];
    const float* ca_bv = (const float*)d_in[17];
    const float* ca_wo = (const float*)d_in[18];
    const float* ca_bo = (const float*)d_in[19];
    const float* ffn_w1 = (const float*)d_in[20];
    const float* ffn_b1 = (const float*)d_in[21];
    const float* ffn_w2 = (const float*)d_in[22];
    const float* ffn_b2 = (const float*)d_in[23];
    const float* n1_g = (const float*)d_in[24];
    const float* n1_b = (const float*)d_in[25];
    const float* n2_g = (const float*)d_in[26];
    const float* n2_b = (const float*)d_in[27];
    const float* n3_g = (const float*)d_in[28];
    const float* n3_b = (const float*)d_in[29];
    (void)ws_size; (void)n_in; (void)in_sizes; (void)out_size;

    const long M_ = 1048576;
    float* W0 = (float*)d_ws;
    float* h   = W0;                 // [0, 2M) fp32
    float* hn  = W0 + 2 * M_;        // [2M, 4M) fp32
    u16* U = (u16*)(W0 + 4 * M_);
    u16* qb     = U;                 // 2M u16
    u16* kb     = U + 2 * M_;        // 2M
    u16* vtb    = U + 4 * M_;        // 2M   [4][512][1024]
    u16* k2b    = U + 6 * M_;        // 1M
    u16* v2tb   = U + 7 * M_;        // 1M   [4][512][512]
    u16* attb   = U + 8 * M_;        // 2M
    u16* hnb    = U + 10 * M_;       // 2M
    u16* midb   = U + 12 * M_;       // 8M
    u16* wsb    = U + 20 * M_;       // 6.55M
    u16* res_tb = U + 27 * M_;       // 1M
    u16* crossb = U + 28 * M_;       // 1M

    // attention partial overlays (regions dead at those pipeline points):
    float* sP0 = h;                          // self z=0: 8MB
    float* sP1 = hn;                         // self z=1: 8MB
    float* sPml = (float*)midb;              // 512KB
    float* cP0 = (float*)(U + 2 * M_);       // cross z=0: kb+vtb (dead)
    float* cP1 = (float*)(U + 12 * M_);      // cross z=1: midb first half
    float* cPml = (float*)(U + 16 * M_);     // midb second half

    const u16* conv_wb = wsb;
    const u16* sa_wqb = wsb + 262144;   // wq,wk,wv contiguous -> fused QKV weight
    const u16* sa_wob = wsb + 1048576;
    const u16* ca_wqb = wsb + 1310720;
    const u16* ca_wkb = wsb + 1572864;  // wk,wv contiguous -> fused KV weight
    const u16* ca_wob = wsb + 2097152;
    const u16* ffn1b = wsb + 2359296, *ffn2b = wsb + 3407872;
    const u16* xb = wsb + 4456448;

    // 0. convert weights + x to bf16
    WSrc ws;
    ws.p[0] = conv_w; ws.p[1] = sa_wq; ws.p[2] = sa_wk; ws.p[3] = sa_wv;
    ws.p[4] = sa_wo; ws.p[5] = ca_wq; ws.p[6] = ca_wk; ws.p[7] = ca_wv;
    ws.p[8] = ca_wo; ws.p[9] = ffn_w1; ws.p[10] = ffn_w2; ws.p[11] = x;
    wconv_kernel<<<6400, 256, 0, stream>>>(ws, wsb);

    // 1. window |max-min|+eps, transposed bf16: res_tb [b][n][c]
    win_kernel<<<4096, 256, 0, stream>>>(gfeat, res_tb, 4 * 512 * 512);

    // 2. conv+relu: crossb[b][o][n]  (64-tile, 256 blocks)
    bgemm64_kernel<2, 1, false, 1><<<dim3(8, 8, 4), 256, 0, stream>>>(
        conv_wb, res_tb, conv_b, nullptr, crossb, 512, 512, 512, 0, 262144, 262144,
        nullptr, nullptr, nullptr, nullptr);

    // 3. fused self-attn QKV projection (128-tile, 384 blocks)
    bgemm128_kernel<1, 0, false, 3><<<dim3(32, 12), 256, 0, stream>>>(
        xb, sa_wqb, sa_bq, nullptr, qb, 4096, 1536, 512, 0, 0, 0,
        kb, vtb, sa_bk, sa_bv);

    // 4. self attention (S=1024): 2 S-chunks of summable partials + combine
    attn_mfma_kernel<<<dim3(64, 8, 2), 512, 0, stream>>>(
        qb, kb, vtb, sP0, sP1, sPml, 1024, 1024);
    attn_combine_kernel<<<1024, 256, 0, stream>>>(sP0, sP1, sPml, attb);

    // 5. out proj + resid x -> h fp32 (64-tile, 512 blocks)
    bgemm64_kernel<1, 0, true, 0><<<dim3(64, 8), 256, 0, stream>>>(
        attb, sa_wob, sa_bo, x, h, 4096, 512, 512, 0, 0, 0,
        nullptr, nullptr, nullptr, nullptr);

    // 6. LN1 -> hn fp32 + hnb bf16
    ln_kernel<false, true><<<4096, 256, 0, stream>>>(h, n1_g, n1_b, hn, hnb);

    // 7. cross-attn: Q proj (scaled), fused K2/V2 proj (64-tile)
    bgemm64_kernel<1, 3, false, 1><<<dim3(64, 8), 256, 0, stream>>>(
        hnb, ca_wqb, ca_bq, nullptr, qb, 4096, 512, 512, 0, 0, 0,
        nullptr, nullptr, nullptr, nullptr);
    bgemm64_kernel<1, 0, false, 4><<<dim3(32, 16), 256, 0, stream>>>(
        crossb, ca_wkb, ca_bk, nullptr, k2b, 2048, 1024, 512, 0, 0, 0,
        nullptr, v2tb, ca_bv, nullptr);

    // 8. cross attention (S=512): 2 S-chunks + combine
    attn_mfma_kernel<<<dim3(64, 8, 2), 512, 0, stream>>>(
        qb, k2b, v2tb, cP0, cP1, cPml, 1024, 512);
    attn_combine_kernel<<<1024, 256, 0, stream>>>(cP0, cP1, cPml, attb);

    // 9. out proj + resid hn -> h fp32 (64-tile)
    bgemm64_kernel<1, 0, true, 0><<<dim3(64, 8), 256, 0, stream>>>(
        attb, ca_wob, ca_bo, hn, h, 4096, 512, 512, 0, 0, 0,
        nullptr, nullptr, nullptr, nullptr);

    // 10. LN2 -> hn fp32 + hnb bf16
    ln_kernel<false, true><<<4096, 256, 0, stream>>>(h, n2_g, n2_b, hn, hnb);

    // 11. FFN up + exact gelu -> midb bf16  [4096,2048] (128-tile, 512 blocks)
    bgemm128_kernel<1, 2, false, 1><<<dim3(32, 16), 256, 0, stream>>>(
        hnb, ffn1b, ffn_b1, nullptr, midb, 4096, 2048, 512, 0, 0, 0,
        nullptr, nullptr, nullptr, nullptr);

    // 12. FFN down + resid hn -> h fp32  [4096,512] K=2048 (64-tile)
    bgemm64_kernel<1, 0, true, 0><<<dim3(64, 8), 256, 0, stream>>>(
        midb, ffn2b, ffn_b2, hn, h, 4096, 512, 2048, 0, 0, 0,
        nullptr, nullptr, nullptr, nullptr);

    // 13. LN3 + transpose -> d_out [B,512,L] fp32
    ln_kernel<true, false><<<4096, 256, 0, stream>>>(h, n3_g, n3_b, (float*)d_out, nullptr);
}

// Round 9
// 199.389 us; speedup vs baseline: 1.2464x; 1.0294x over previous
//
#include <hip/hip_runtime.h>
#include <hip/hip_bf16.h>
#include <math.h>

#define SCALE_Q 0.25504522f  // 1/sqrt(32) * log2(e)  (Q pre-scale for exp2 softmax)

typedef unsigned short u16;
typedef unsigned int u32;
typedef __attribute__((ext_vector_type(8))) short bshort8;
typedef __attribute__((ext_vector_type(4))) short sshort4;
typedef __attribute__((ext_vector_type(4))) float f32x4;
typedef __attribute__((ext_vector_type(4))) u32 u32x4;

__device__ inline u16 f2b(float f) {  // fp32 -> bf16 RNE
    union { float f; uint32_t u; } c;
    c.f = f;
    uint32_t u = c.u;
    return (u16)((u + 0x7fffu + ((u >> 16) & 1u)) >> 16);
}

__device__ __forceinline__ u32 cvtpk(float a, float b) {  // {lo=bf16(a), hi=bf16(b)}
    u32 r;
    asm("v_cvt_pk_bf16_f32 %0, %1, %2" : "=v"(r) : "v"(a), "v"(b));
    return r;
}

__device__ __forceinline__ float exp2c(float s) {  // 2^min(s,100)
    float c = fminf(s, 100.f);
    float r;
    asm("v_exp_f32 %0, %1" : "=v"(r) : "v"(c));
    return r;
}

__device__ inline void gload_lds16(const void* g, void* lds) {
    __builtin_amdgcn_global_load_lds(
        (const __attribute__((address_space(1))) void*)g,
        (__attribute__((address_space(3))) void*)lds, 16, 0, 0);
}

// ---------------- batched fp32->bf16 convert (11 weights + x) ----------------
struct WSrc { const float* p[12]; };
__global__ __launch_bounds__(256) void wconv_kernel(WSrc s, u16* __restrict__ dst) {
    long e = ((long)blockIdx.x * 256 + threadIdx.x) * 4;
    if (e >= 6553600) return;
    int w; long base;
    if (e < 2359296)      { w = (int)(e >> 18); base = (long)w << 18; }
    else if (e < 3407872) { w = 9;  base = 2359296; }
    else if (e < 4456448) { w = 10; base = 3407872; }
    else                  { w = 11; base = 4456448; }
    float4 v = *(const float4*)(s.p[w] + (e - base));
    dst[e + 0] = f2b(v.x); dst[e + 1] = f2b(v.y);
    dst[e + 2] = f2b(v.z); dst[e + 3] = f2b(v.w);
}

// ---------------- window |max-min| + eps -> transposed bf16 [b][n][c] ----------------
__global__ __launch_bounds__(256) void win_kernel(const float* __restrict__ G,
                                                  u16* __restrict__ Rt, int total) {
    int i = blockIdx.x * 256 + threadIdx.x;
    if (i >= total) return;
    const float4* p = reinterpret_cast<const float4*>(G) + (size_t)i * 2;
    float4 a = p[0], b = p[1];
    float mx = fmaxf(fmaxf(fmaxf(a.x, a.y), fmaxf(a.z, a.w)),
                     fmaxf(fmaxf(b.x, b.y), fmaxf(b.z, b.w)));
    float mn = fminf(fminf(fminf(a.x, a.y), fminf(a.z, a.w)),
                     fminf(fminf(b.x, b.y), fminf(b.z, b.w)));
    int b_ = i >> 18, c = (i >> 9) & 511, n = i & 511;
    Rt[((long)(b_ * 512 + n) << 9) + c] = f2b(fabsf(mx - mn) + 1e-6f);
}

// ================= shared epilogue =================
template <int BIASMODE, int ACT, bool RESID, int OUTMODE>
__device__ __forceinline__ void gemm_epilogue_elem(
    float v, int row, int col, int N, long zoff,
    const float* bias, const float* Rres, void* Cout,
    u16* D1, u16* D2, const float* bias1, const float* bias2) {
    if (OUTMODE == 3) {  // fused QKV split
        int grp = col >> 9, c = col & 511;
        float bb = (grp == 0) ? bias[c] : (grp == 1) ? bias1[c] : bias2[c];
        float vv = v + bb;
        if (grp == 0)
            ((u16*)Cout)[(long)row * 512 + c] = f2b(vv * SCALE_Q);
        else if (grp == 1)
            D1[(long)row * 512 + c] = f2b(vv);
        else
            D2[((long)((row >> 10) * 512 + c) << 10) + (row & 1023)] = f2b(vv);
    } else if (OUTMODE == 4) {  // fused KV split
        int grp = col >> 9, c = col & 511;
        float vv = v + ((grp == 0) ? bias[c] : bias1[c]);
        if (grp == 0)
            ((u16*)Cout)[(long)row * 512 + c] = f2b(vv);
        else
            D2[((long)((row >> 9) * 512 + c) << 9) + (row & 511)] = f2b(vv);
    } else {
        if (BIASMODE == 1) v += bias[col];
        if (BIASMODE == 2) v += bias[row];
        if (ACT == 1) v = fmaxf(v, 0.f);
        if (ACT == 2) v = 0.5f * v * (1.f + erff(v * 0.70710678118654752f));
        if (ACT == 3) v *= SCALE_Q;
        if (RESID) v += Rres[(long)row * N + col];
        long off = zoff + (long)row * N + col;
        if (OUTMODE == 1) ((u16*)Cout)[off] = f2b(v);
        else              ((float*)Cout)[off] = v;
    }
}

// ---------------- bf16 MFMA GEMM, 64x64 tile, double-buffered counted-vmcnt ---------
// 4 gloads/thread/tile stay in flight across the barrier (s_waitcnt vmcnt(4)).
template <int BIASMODE, int ACT, bool RESID, int OUTMODE>
__global__ __launch_bounds__(256) void bgemm64_kernel(
    const u16* __restrict__ A, const u16* __restrict__ Bt,
    const float* __restrict__ bias, const float* __restrict__ Rres,
    void* __restrict__ Cout, int M, int N, int K,
    long sA, long sB, long sC,
    u16* __restrict__ D1, u16* __restrict__ D2,
    const float* __restrict__ bias1, const float* __restrict__ bias2) {
    A  += (long)blockIdx.z * sA;
    Bt += (long)blockIdx.z * sB;
    __shared__ u16 As[2][64 * 64];
    __shared__ u16 Bs[2][64 * 64];
    int tid = threadIdx.x;
    int lane = tid & 63, wv = tid >> 6;
    int wr = wv >> 1, wc = wv & 1;
    int m0 = blockIdx.x * 64, n0 = blockIdx.y * 64;
    f32x4 acc[2][2] = {};
    int srow = lane >> 3;
    int selem = ((lane & 7) ^ srow) << 3;

    auto STAGE = [&](int buf, int k0) {
        #pragma unroll
        for (int i = 0; i < 2; i++) {
            int roff = i * 32 + wv * 8;
            gload_lds16(A + (long)(m0 + roff + srow) * K + k0 + selem,
                        (char*)As[buf] + roff * 128);
            gload_lds16(Bt + (long)(n0 + roff + srow) * K + k0 + selem,
                        (char*)Bs[buf] + roff * 128);
        }
    };

    int NT = K >> 6;
    STAGE(0, 0);
    int cur = 0;
    for (int kt = 0; kt < NT; ++kt) {
        if (kt + 1 < NT) {
            STAGE(cur ^ 1, (kt + 1) << 6);
            asm volatile("s_waitcnt vmcnt(4)\ns_barrier" ::: "memory");
        } else {
            asm volatile("s_waitcnt vmcnt(0)\ns_barrier" ::: "memory");
        }
        #pragma unroll
        for (int ks = 0; ks < 2; ks++) {
            bshort8 af[2], bf[2];
            int kbo = ks * 64 + ((lane >> 4) << 4);
            #pragma unroll
            for (int f = 0; f < 2; f++) {
                int arow = wr * 32 + f * 16 + (lane & 15);
                af[f] = *(const bshort8*)((const char*)As[cur] + arow * 128 +
                                          (kbo ^ ((arow & 7) << 4)));
                int brow = wc * 32 + f * 16 + (lane & 15);
                bf[f] = *(const bshort8*)((const char*)Bs[cur] + brow * 128 +
                                          (kbo ^ ((brow & 7) << 4)));
            }
            #pragma unroll
            for (int fi = 0; fi < 2; fi++)
                #pragma unroll
                for (int fj = 0; fj < 2; fj++)
                    acc[fi][fj] = __builtin_amdgcn_mfma_f32_16x16x32_bf16(
                        af[fi], bf[fj], acc[fi][fj], 0, 0, 0);
        }
        asm volatile("s_barrier" ::: "memory");
        cur ^= 1;
    }
    long zoff = (long)blockIdx.z * sC;
    #pragma unroll
    for (int fi = 0; fi < 2; fi++)
        #pragma unroll
        for (int fj = 0; fj < 2; fj++)
            #pragma unroll
            for (int r = 0; r < 4; r++) {
                int row = m0 + wr * 32 + fi * 16 + ((lane >> 4) << 2) + r;
                int col = n0 + wc * 32 + fj * 16 + (lane & 15);
                gemm_epilogue_elem<BIASMODE, ACT, RESID, OUTMODE>(
                    acc[fi][fj][r], row, col, N, zoff, bias, Rres, Cout,
                    D1, D2, bias1, bias2);
            }
}

// ---------------- fused MFMA flash attention: 8 waves, S-split, no-max exp2 ---------
// K LDS chunk swizzle f(row) = ((row>>3)&3)^((row>>1)&3): 16-lane K reads spread
// 2-per-bank-group (conflict-free); staging source pre-swizzled to match.
__global__ __launch_bounds__(512) void attn_mfma_kernel(
    const u16* __restrict__ Q, const u16* __restrict__ K,
    const u16* __restrict__ Vt, float* __restrict__ Pacc0,
    float* __restrict__ Pacc1, float* __restrict__ Pml, int L, int S) {
    __shared__ __align__(16) u16 Ks[2][2048];
    __shared__ __align__(16) u16 Vs[2][2048];
    int bh = blockIdx.x;
    int b = bh >> 4, h = bh & 15;
    int z = blockIdx.z;
    int tid = threadIdx.x;
    int lane = tid & 63, wv = tid >> 6;
    int q0 = blockIdx.y * 128 + wv * 16;
    int qr = lane & 15, g = lane >> 4, g8 = g * 8;
    int kperm = 8 * (qr >> 2) + (qr & 3);
    int sbeg = z * (S >> 1);
    int nt = S >> 7;  // tiles of 64 keys in this half

    const u16* Kb = K + (long)b * S * 512 + h * 32;
    const u16* Vb = Vt + ((long)b * 512 + h * 32) * S;
    bshort8 qf = *(const bshort8*)(Q + ((long)(b * L + q0 + qr)) * 512 + h * 32 + g8);

    const u16* src;
    long step;
    char *d0, *d1;
    if (wv < 4) {
        int rk = wv * 16 + (lane >> 2);
        int f = ((rk >> 3) & 3) ^ ((rk >> 1) & 3);
        int sc = (lane & 3) ^ f;
        src = Kb + (long)(sbeg + rk) * 512 + sc * 8;
        step = (long)64 * 512;
        d0 = (char*)Ks[0] + wv * 1024;
        d1 = (char*)Ks[1] + wv * 1024;
    } else {
        int rv = (wv - 4) * 8 + (lane >> 3);
        int sc = (lane & 7) ^ (lane >> 3);
        src = Vb + (long)rv * S + sbeg + sc * 8;
        step = 64;
        d0 = (char*)Vs[0] + (wv - 4) * 1024;
        d1 = (char*)Vs[1] + (wv - 4) * 1024;
    }

    f32x4 acc0 = {}, acc1 = {};
    float lsum = 0.f;
    int f0 = (qr >> 2) ^ ((qr >> 1) & 1);
    int f1 = f0 ^ 2;

    gload_lds16(src, d0);
    int cur = 0;
    for (int t = 0; t < nt; ++t) {
        if (t + 1 < nt) {
            gload_lds16(src + (long)(t + 1) * step, cur ? d0 : d1);
            asm volatile("s_waitcnt vmcnt(1)\ns_barrier" ::: "memory");
        } else {
            asm volatile("s_waitcnt vmcnt(0)\ns_barrier" ::: "memory");
        }
        const char* Kt = (const char*)Ks[cur];
        const char* Vl = (const char*)Vs[cur];
        bshort8 a0 = *(const bshort8*)(Kt + kperm * 64 + ((g ^ f0) << 4));
        bshort8 a1 = *(const bshort8*)(Kt + (kperm + 4) * 64 + ((g ^ f1) << 4));
        bshort8 a2 = *(const bshort8*)(Kt + (kperm + 32) * 64 + ((g ^ f0) << 4));
        bshort8 a3 = *(const bshort8*)(Kt + (kperm + 36) * 64 + ((g ^ f1) << 4));
        bshort8 v00 = *(const bshort8*)(Vl + qr * 128 + ((g ^ (qr & 7)) << 4));
        bshort8 v01 = *(const bshort8*)(Vl + qr * 128 + (((g + 4) ^ (qr & 7)) << 4));
        bshort8 v10 = *(const bshort8*)(Vl + (16 + qr) * 128 + ((g ^ (qr & 7)) << 4));
        bshort8 v11 = *(const bshort8*)(Vl + (16 + qr) * 128 + (((g + 4) ^ (qr & 7)) << 4));
        f32x4 zz = {0.f, 0.f, 0.f, 0.f};
        f32x4 st0 = __builtin_amdgcn_mfma_f32_16x16x32_bf16(a0, qf, zz, 0, 0, 0);
        f32x4 st1 = __builtin_amdgcn_mfma_f32_16x16x32_bf16(a1, qf, zz, 0, 0, 0);
        f32x4 st2 = __builtin_amdgcn_mfma_f32_16x16x32_bf16(a2, qf, zz, 0, 0, 0);
        f32x4 st3 = __builtin_amdgcn_mfma_f32_16x16x32_bf16(a3, qf, zz, 0, 0, 0);
        float p0[4], p1[4], p2[4], p3[4];
        #pragma unroll
        for (int r = 0; r < 4; r++) {
            p0[r] = exp2c(st0[r]);
            p1[r] = exp2c(st1[r]);
            p2[r] = exp2c(st2[r]);
            p3[r] = exp2c(st3[r]);
        }
        float ps = ((p0[0] + p0[1]) + (p0[2] + p0[3])) + ((p1[0] + p1[1]) + (p1[2] + p1[3])) +
                   ((p2[0] + p2[1]) + (p2[2] + p2[3])) + ((p3[0] + p3[1]) + (p3[2] + p3[3]));
        lsum += ps;
        u32x4 P0 = { cvtpk(p0[0], p0[1]), cvtpk(p0[2], p0[3]),
                     cvtpk(p1[0], p1[1]), cvtpk(p1[2], p1[3]) };
        u32x4 P1 = { cvtpk(p2[0], p2[1]), cvtpk(p2[2], p2[3]),
                     cvtpk(p3[0], p3[1]), cvtpk(p3[2], p3[3]) };
        bshort8 pf0 = *(bshort8*)&P0;
        bshort8 pf1 = *(bshort8*)&P1;
        acc0 = __builtin_amdgcn_mfma_f32_16x16x32_bf16(v00, pf0, acc0, 0, 0, 0);
        acc0 = __builtin_amdgcn_mfma_f32_16x16x32_bf16(v01, pf1, acc0, 0, 0, 0);
        acc1 = __builtin_amdgcn_mfma_f32_16x16x32_bf16(v10, pf0, acc1, 0, 0, 0);
        acc1 = __builtin_amdgcn_mfma_f32_16x16x32_bf16(v11, pf1, acc1, 0, 0, 0);
        asm volatile("s_barrier" ::: "memory");
        cur ^= 1;
    }

    lsum += __shfl_xor(lsum, 16);
    lsum += __shfl_xor(lsum, 32);
    float* PZ = z ? Pacc1 : Pacc0;
    float* pa = PZ + (((long)b * L + q0 + qr) << 9) + h * 32 + g * 4;
    *(f32x4*)pa = acc0;
    *(f32x4*)(pa + 16) = acc1;
    if (g == 0) Pml[(long)z * 65536 + (long)bh * L + q0 + qr] = lsum;
}

// ---------------- attention combine: O = (P0+P1)/(l0+l1) -> bf16 ----------------
__global__ __launch_bounds__(256) void attn_combine_kernel(
    const float* __restrict__ P0, const float* __restrict__ P1,
    const float* __restrict__ Pml, u16* __restrict__ O) {
    long e = ((long)blockIdx.x * 256 + threadIdx.x) * 8;  // over 4096x512 f32
    int q = (int)(e >> 9);
    int c = (int)(e & 511);
    int h = c >> 5;
    int b = q >> 10, l = q & 1023;
    int bh = b * 16 + h;
    float l0 = Pml[bh * 1024 + l];
    float l1 = Pml[65536 + bh * 1024 + l];
    float inv = 1.f / (l0 + l1);
    f32x4 x0 = *(const f32x4*)(P0 + e);
    f32x4 x1 = *(const f32x4*)(P0 + e + 4);
    f32x4 y0 = *(const f32x4*)(P1 + e);
    f32x4 y1 = *(const f32x4*)(P1 + e + 4);
    sshort4 o0, o1;
    #pragma unroll
    for (int r = 0; r < 4; r++) {
        o0[r] = (short)f2b((x0[r] + y0[r]) * inv);
        o1[r] = (short)f2b((x1[r] + y1[r]) * inv);
    }
    *(sshort4*)(O + e) = o0;
    *(sshort4*)(O + e + 4) = o1;
}

// ---------------- layernorm over 512; optional bf16 dual-store / transposed out ------
template <bool TRANS, bool DUAL>
__global__ __launch_bounds__(256) void ln_kernel(const float* __restrict__ X,
                                                 const float* __restrict__ g,
                                                 const float* __restrict__ bt,
                                                 float* __restrict__ Y,
                                                 u16* __restrict__ Yb) {
    int row = blockIdx.x;
    const float* xr = X + (long)row * 512;
    int t = threadIdx.x;
    float x0 = xr[t], x1 = xr[t + 256];
    float s = x0 + x1, ss = x0 * x0 + x1 * x1;
    #pragma unroll
    for (int off = 32; off > 0; off >>= 1) {
        s += __shfl_down(s, off);
        ss += __shfl_down(ss, off);
    }
    __shared__ float sred[4], ssred[4];
    int wid = t >> 6;
    if ((t & 63) == 0) { sred[wid] = s; ssred[wid] = ss; }
    __syncthreads();
    float ts = sred[0] + sred[1] + sred[2] + sred[3];
    float tss = ssred[0] + ssred[1] + ssred[2] + ssred[3];
    float mean = ts * (1.f / 512.f);
    float var = tss * (1.f / 512.f) - mean * mean;
    float rstd = rsqrtf(var + 1e-5f);
    float y0 = (x0 - mean) * rstd * g[t] + bt[t];
    float y1 = (x1 - mean) * rstd * g[t + 256] + bt[t + 256];
    if (TRANS) {
        int b = row >> 10, l = row & 1023;
        Y[((long)b * 512 + t) * 1024 + l] = y0;
        Y[((long)b * 512 + t + 256) * 1024 + l] = y1;
    } else {
        Y[(long)row * 512 + t] = y0;
        Y[(long)row * 512 + t + 256] = y1;
    }
    if (DUAL) {
        Yb[(long)row * 512 + t] = f2b(y0);
        Yb[(long)row * 512 + t + 256] = f2b(y1);
    }
}

extern "C" void kernel_launch(void* const* d_in, const int* in_sizes, int n_in,
                              void* d_out, int out_size, void* d_ws, size_t ws_size,
                              hipStream_t stream) {
    const float* x      = (const float*)d_in[0];
    const float* gfeat  = (const float*)d_in[1];
    const float* conv_w = (const float*)d_in[2];
    const float* conv_b = (const float*)d_in[3];
    const float* sa_wq = (const float*)d_in[4];
    const float* sa_bq = (const float*)d_in[5];
    const float* sa_wk = (const float*)d_in[6];
    const float* sa_bk = (const float*)d_in[7];
    const float* sa_wv = (const float*)d_in[8];
    const float* sa_bv = (const float*)d_in[9];
    const float* sa_wo = (const float*)d_in[10];
    const float* sa_bo = (const float*)d_in[11];
    const float* ca_wq = (const float*)d_in[12];
    const float* ca_bq = (const float*)d_in[13];
    const float* ca_wk = (const float*)d_in[14];
    const float* ca_bk = (const float*)d_in[15];
    const float* ca_wv = (const float*)d_in[16];
    const float* ca_bv = (const float*)d_in[17];
    const float* ca_wo = (const float*)d_in[18];
    const float* ca_bo = (const float*)d_in[19];
    const float* ffn_w1 = (const float*)d_in[20];
    const float* ffn_b1 = (const float*)d_in[21];
    const float* ffn_w2 = (const float*)d_in[22];
    const float* ffn_b2 = (const float*)d_in[23];
    const float* n1_g = (const float*)d_in[24];
    const float* n1_b = (const float*)d_in[25];
    const float* n2_g = (const float*)d_in[26];
    const float* n2_b = (const float*)d_in[27];
    const float* n3_g = (const float*)d_in[28];
    const float* n3_b = (const float*)d_in[29];
    (void)ws_size; (void)n_in; (void)in_sizes; (void)out_size;

    const long M_ = 1048576;
    float* W0 = (float*)d_ws;
    float* h   = W0;                 // [0, 2M) fp32
    float* hn  = W0 + 2 * M_;        // [2M, 4M) fp32
    u16* U = (u16*)(W0 + 4 * M_);
    u16* qb     = U;                 // 2M u16
    u16* kb     = U + 2 * M_;        // 2M
    u16* vtb    = U + 4 * M_;        // 2M   [4][512][1024]
    u16* k2b    = U + 6 * M_;        // 1M
    u16* v2tb   = U + 7 * M_;        // 1M   [4][512][512]
    u16* attb   = U + 8 * M_;        // 2M
    u16* hnb    = U + 10 * M_;       // 2M
    u16* midb   = U + 12 * M_;       // 8M
    u16* wsb    = U + 20 * M_;       // 6.55M
    u16* res_tb = U + 27 * M_;       // 1M
    u16* crossb = U + 28 * M_;       // 1M

    // attention partial overlays (regions dead at those pipeline points):
    float* sP0 = h;                          // self z=0: 8MB
    float* sP1 = hn;                         // self z=1: 8MB
    float* sPml = (float*)midb;              // 512KB
    float* cP0 = (float*)(U + 2 * M_);       // cross z=0: kb+vtb (dead)
    float* cP1 = (float*)(U + 12 * M_);      // cross z=1: midb first half
    float* cPml = (float*)(U + 16 * M_);     // midb second half

    const u16* conv_wb = wsb;
    const u16* sa_wqb = wsb + 262144;   // wq,wk,wv contiguous -> fused QKV weight
    const u16* sa_wob = wsb + 1048576;
    const u16* ca_wqb = wsb + 1310720;
    const u16* ca_wkb = wsb + 1572864;  // wk,wv contiguous -> fused KV weight
    const u16* ca_wob = wsb + 2097152;
    const u16* ffn1b = wsb + 2359296, *ffn2b = wsb + 3407872;
    const u16* xb = wsb + 4456448;

    // 0. convert weights + x to bf16
    WSrc ws;
    ws.p[0] = conv_w; ws.p[1] = sa_wq; ws.p[2] = sa_wk; ws.p[3] = sa_wv;
    ws.p[4] = sa_wo; ws.p[5] = ca_wq; ws.p[6] = ca_wk; ws.p[7] = ca_wv;
    ws.p[8] = ca_wo; ws.p[9] = ffn_w1; ws.p[10] = ffn_w2; ws.p[11] = x;
    wconv_kernel<<<6400, 256, 0, stream>>>(ws, wsb);

    // 1. window |max-min|+eps, transposed bf16: res_tb [b][n][c]
    win_kernel<<<4096, 256, 0, stream>>>(gfeat, res_tb, 4 * 512 * 512);

    // 2. conv+relu: crossb[b][o][n]  (256 blocks)
    bgemm64_kernel<2, 1, false, 1><<<dim3(8, 8, 4), 256, 0, stream>>>(
        conv_wb, res_tb, conv_b, nullptr, crossb, 512, 512, 512, 0, 262144, 262144,
        nullptr, nullptr, nullptr, nullptr);

    // 3. fused self-attn QKV projection (1536 blocks)
    bgemm64_kernel<1, 0, false, 3><<<dim3(64, 24), 256, 0, stream>>>(
        xb, sa_wqb, sa_bq, nullptr, qb, 4096, 1536, 512, 0, 0, 0,
        kb, vtb, sa_bk, sa_bv);

    // 4. self attention (S=1024): 2 S-chunks of summable partials + combine
    attn_mfma_kernel<<<dim3(64, 8, 2), 512, 0, stream>>>(
        qb, kb, vtb, sP0, sP1, sPml, 1024, 1024);
    attn_combine_kernel<<<1024, 256, 0, stream>>>(sP0, sP1, sPml, attb);

    // 5. out proj + resid x -> h fp32 (512 blocks)
    bgemm64_kernel<1, 0, true, 0><<<dim3(64, 8), 256, 0, stream>>>(
        attb, sa_wob, sa_bo, x, h, 4096, 512, 512, 0, 0, 0,
        nullptr, nullptr, nullptr, nullptr);

    // 6. LN1 -> hn fp32 + hnb bf16
    ln_kernel<false, true><<<4096, 256, 0, stream>>>(h, n1_g, n1_b, hn, hnb);

    // 7. cross-attn: Q proj (scaled), fused K2/V2 proj
    bgemm64_kernel<1, 3, false, 1><<<dim3(64, 8), 256, 0, stream>>>(
        hnb, ca_wqb, ca_bq, nullptr, qb, 4096, 512, 512, 0, 0, 0,
        nullptr, nullptr, nullptr, nullptr);
    bgemm64_kernel<1, 0, false, 4><<<dim3(32, 16), 256, 0, stream>>>(
        crossb, ca_wkb, ca_bk, nullptr, k2b, 2048, 1024, 512, 0, 0, 0,
        nullptr, v2tb, ca_bv, nullptr);

    // 8. cross attention (S=512): 2 S-chunks + combine
    attn_mfma_kernel<<<dim3(64, 8, 2), 512, 0, stream>>>(
        qb, k2b, v2tb, cP0, cP1, cPml, 1024, 512);
    attn_combine_kernel<<<1024, 256, 0, stream>>>(cP0, cP1, cPml, attb);

    // 9. out proj + resid hn -> h fp32
    bgemm64_kernel<1, 0, true, 0><<<dim3(64, 8), 256, 0, stream>>>(
        attb, ca_wob, ca_bo, hn, h, 4096, 512, 512, 0, 0, 0,
        nullptr, nullptr, nullptr, nullptr);

    // 10. LN2 -> hn fp32 + hnb bf16
    ln_kernel<false, true><<<4096, 256, 0, stream>>>(h, n2_g, n2_b, hn, hnb);

    // 11. FFN up + exact gelu -> midb bf16  [4096,2048] (2048 blocks)
    bgemm64_kernel<1, 2, false, 1><<<dim3(64, 32), 256, 0, stream>>>(
        hnb, ffn1b, ffn_b1, nullptr, midb, 4096, 2048, 512, 0, 0, 0,
        nullptr, nullptr, nullptr, nullptr);

    // 12. FFN down + resid hn -> h fp32  [4096,512] K=2048
    bgemm64_kernel<1, 0, true, 0><<<dim3(64, 8), 256, 0, stream>>>(
        midb, ffn2b, ffn_b2, hn, h, 4096, 512, 2048, 0, 0, 0,
        nullptr, nullptr, nullptr, nullptr);

    // 13. LN3 + transpose -> d_out [B,512,L] fp32
    ln_kernel<true, false><<<4096, 256, 0, stream>>>(h, n3_g, n3_b, (float*)d_out, nullptr);
}

// Round 10
// 173.874 us; speedup vs baseline: 1.4293x; 1.1467x over previous
//
#include <hip/hip_runtime.h>
#include <hip/hip_bf16.h>
#include <math.h>

#define SCALE_Q 0.25504522f  // 1/sqrt(32) * log2(e)  (Q pre-scale for exp2 softmax)

typedef unsigned short u16;
typedef unsigned int u32;
typedef __attribute__((ext_vector_type(8))) short bshort8;
typedef __attribute__((ext_vector_type(4))) short sshort4;
typedef __attribute__((ext_vector_type(4))) float f32x4;
typedef __attribute__((ext_vector_type(4))) u32 u32x4;

__device__ inline u16 f2b(float f) {  // fp32 -> bf16 RNE
    union { float f; uint32_t u; } c;
    c.f = f;
    uint32_t u = c.u;
    return (u16)((u + 0x7fffu + ((u >> 16) & 1u)) >> 16);
}

__device__ __forceinline__ u32 cvtpk(float a, float b) {  // {lo=bf16(a), hi=bf16(b)}
    u32 r;
    asm("v_cvt_pk_bf16_f32 %0, %1, %2" : "=v"(r) : "v"(a), "v"(b));
    return r;
}

__device__ __forceinline__ float exp2c(float s) {  // 2^min(s,100)
    float c = fminf(s, 100.f);
    float r;
    asm("v_exp_f32 %0, %1" : "=v"(r) : "v"(c));
    return r;
}

__device__ inline void gload_lds16(const void* g, void* lds) {
    __builtin_amdgcn_global_load_lds(
        (const __attribute__((address_space(1))) void*)g,
        (__attribute__((address_space(3))) void*)lds, 16, 0, 0);
}

// ---------------- batched fp32->bf16 convert (11 weights + x) ----------------
struct WSrc { const float* p[12]; };
__global__ __launch_bounds__(256) void wconv_kernel(WSrc s, u16* __restrict__ dst) {
    long e = ((long)blockIdx.x * 256 + threadIdx.x) * 4;
    if (e >= 6553600) return;
    int w; long base;
    if (e < 2359296)      { w = (int)(e >> 18); base = (long)w << 18; }
    else if (e < 3407872) { w = 9;  base = 2359296; }
    else if (e < 4456448) { w = 10; base = 3407872; }
    else                  { w = 11; base = 4456448; }
    float4 v = *(const float4*)(s.p[w] + (e - base));
    dst[e + 0] = f2b(v.x); dst[e + 1] = f2b(v.y);
    dst[e + 2] = f2b(v.z); dst[e + 3] = f2b(v.w);
}

// ---------------- window |max-min| + eps -> transposed bf16 [b][n][c] ----------------
__global__ __launch_bounds__(256) void win_kernel(const float* __restrict__ G,
                                                  u16* __restrict__ Rt, int total) {
    int i = blockIdx.x * 256 + threadIdx.x;
    if (i >= total) return;
    const float4* p = reinterpret_cast<const float4*>(G) + (size_t)i * 2;
    float4 a = p[0], b = p[1];
    float mx = fmaxf(fmaxf(fmaxf(a.x, a.y), fmaxf(a.z, a.w)),
                     fmaxf(fmaxf(b.x, b.y), fmaxf(b.z, b.w)));
    float mn = fminf(fminf(fminf(a.x, a.y), fminf(a.z, a.w)),
                     fminf(fminf(b.x, b.y), fminf(b.z, b.w)));
    int b_ = i >> 18, c = (i >> 9) & 511, n = i & 511;
    Rt[((long)(b_ * 512 + n) << 9) + c] = f2b(fabsf(mx - mn) + 1e-6f);
}

// ================= shared epilogue =================
template <int BIASMODE, int ACT, bool RESID, int OUTMODE>
__device__ __forceinline__ void gemm_epilogue_elem(
    float v, int row, int col, int N, long zoff,
    const float* bias, const float* Rres, void* Cout,
    u16* D1, u16* D2, const float* bias1, const float* bias2) {
    if (OUTMODE == 3) {  // fused QKV split
        int grp = col >> 9, c = col & 511;
        float bb = (grp == 0) ? bias[c] : (grp == 1) ? bias1[c] : bias2[c];
        float vv = v + bb;
        if (grp == 0)
            ((u16*)Cout)[(long)row * 512 + c] = f2b(vv * SCALE_Q);
        else if (grp == 1)
            D1[(long)row * 512 + c] = f2b(vv);
        else
            D2[((long)((row >> 10) * 512 + c) << 10) + (row & 1023)] = f2b(vv);
    } else if (OUTMODE == 4) {  // fused KV split
        int grp = col >> 9, c = col & 511;
        float vv = v + ((grp == 0) ? bias[c] : bias1[c]);
        if (grp == 0)
            ((u16*)Cout)[(long)row * 512 + c] = f2b(vv);
        else
            D2[((long)((row >> 9) * 512 + c) << 9) + (row & 511)] = f2b(vv);
    } else {
        if (BIASMODE == 1) v += bias[col];
        if (BIASMODE == 2) v += bias[row];
        if (ACT == 1) v = fmaxf(v, 0.f);
        if (ACT == 2) v = 0.5f * v * (1.f + erff(v * 0.70710678118654752f));
        if (ACT == 3) v *= SCALE_Q;
        if (RESID) v += Rres[(long)row * N + col];
        long off = zoff + (long)row * N + col;
        if (OUTMODE == 1) ((u16*)Cout)[off] = f2b(v);
        else              ((float*)Cout)[off] = v;
    }
}

// ---------------- bf16 MFMA GEMM, 64x64 tile, double-buffered counted-vmcnt ---------
template <int BIASMODE, int ACT, bool RESID, int OUTMODE>
__global__ __launch_bounds__(256) void bgemm64_kernel(
    const u16* __restrict__ A, const u16* __restrict__ Bt,
    const float* __restrict__ bias, const float* __restrict__ Rres,
    void* __restrict__ Cout, int M, int N, int K,
    long sA, long sB, long sC,
    u16* __restrict__ D1, u16* __restrict__ D2,
    const float* __restrict__ bias1, const float* __restrict__ bias2) {
    A  += (long)blockIdx.z * sA;
    Bt += (long)blockIdx.z * sB;
    __shared__ u16 As[2][64 * 64];
    __shared__ u16 Bs[2][64 * 64];
    int tid = threadIdx.x;
    int lane = tid & 63, wv = tid >> 6;
    int wr = wv >> 1, wc = wv & 1;
    int m0 = blockIdx.x * 64, n0 = blockIdx.y * 64;
    f32x4 acc[2][2] = {};
    int srow = lane >> 3;
    int selem = ((lane & 7) ^ srow) << 3;

    auto STAGE = [&](int buf, int k0) {
        #pragma unroll
        for (int i = 0; i < 2; i++) {
            int roff = i * 32 + wv * 8;
            gload_lds16(A + (long)(m0 + roff + srow) * K + k0 + selem,
                        (char*)As[buf] + roff * 128);
            gload_lds16(Bt + (long)(n0 + roff + srow) * K + k0 + selem,
                        (char*)Bs[buf] + roff * 128);
        }
    };

    int NT = K >> 6;
    STAGE(0, 0);
    int cur = 0;
    for (int kt = 0; kt < NT; ++kt) {
        if (kt + 1 < NT) {
            STAGE(cur ^ 1, (kt + 1) << 6);
            asm volatile("s_waitcnt vmcnt(4)\ns_barrier" ::: "memory");
        } else {
            asm volatile("s_waitcnt vmcnt(0)\ns_barrier" ::: "memory");
        }
        #pragma unroll
        for (int ks = 0; ks < 2; ks++) {
            bshort8 af[2], bf[2];
            int kbo = ks * 64 + ((lane >> 4) << 4);
            #pragma unroll
            for (int f = 0; f < 2; f++) {
                int arow = wr * 32 + f * 16 + (lane & 15);
                af[f] = *(const bshort8*)((const char*)As[cur] + arow * 128 +
                                          (kbo ^ ((arow & 7) << 4)));
                int brow = wc * 32 + f * 16 + (lane & 15);
                bf[f] = *(const bshort8*)((const char*)Bs[cur] + brow * 128 +
                                          (kbo ^ ((brow & 7) << 4)));
            }
            #pragma unroll
            for (int fi = 0; fi < 2; fi++)
                #pragma unroll
                for (int fj = 0; fj < 2; fj++)
                    acc[fi][fj] = __builtin_amdgcn_mfma_f32_16x16x32_bf16(
                        af[fi], bf[fj], acc[fi][fj], 0, 0, 0);
        }
        asm volatile("s_barrier" ::: "memory");
        cur ^= 1;
    }
    long zoff = (long)blockIdx.z * sC;
    #pragma unroll
    for (int fi = 0; fi < 2; fi++)
        #pragma unroll
        for (int fj = 0; fj < 2; fj++)
            #pragma unroll
            for (int r = 0; r < 4; r++) {
                int row = m0 + wr * 32 + fi * 16 + ((lane >> 4) << 2) + r;
                int col = n0 + wc * 32 + fj * 16 + (lane & 15);
                gemm_epilogue_elem<BIASMODE, ACT, RESID, OUTMODE>(
                    acc[fi][fj][r], row, col, N, zoff, bias, Rres, Cout,
                    D1, D2, bias1, bias2);
            }
}

// ---------------- fused MFMA flash attention: 8 waves, single-pass, no-max exp2 -----
// Q [B,L,512] bf16 (pre-scaled), K [B,S,512] bf16, Vt [B,512,S] bf16, O bf16.
// Grid (bh=64, L/128), 512 threads; block = 128 queries over the FULL key range.
// Waves 0-3 stage K (64x32), waves 4-7 stage V^T (32x64), double-buffered,
// counted s_waitcnt vmcnt(1). Output normalized in-kernel -> attb.
__global__ __launch_bounds__(512) void attn_mfma_kernel(
    const u16* __restrict__ Q, const u16* __restrict__ K,
    const u16* __restrict__ Vt, u16* __restrict__ O, int L, int S) {
    __shared__ __align__(16) u16 Ks[2][2048];
    __shared__ __align__(16) u16 Vs[2][2048];
    int bh = blockIdx.x;
    int b = bh >> 4, h = bh & 15;
    int tid = threadIdx.x;
    int lane = tid & 63, wv = tid >> 6;
    int q0 = blockIdx.y * 128 + wv * 16;
    int qr = lane & 15, g = lane >> 4, g8 = g * 8;
    int kperm = 8 * (qr >> 2) + (qr & 3);
    int nt = S >> 6;

    const u16* Kb = K + (long)b * S * 512 + h * 32;
    const u16* Vb = Vt + ((long)b * 512 + h * 32) * S;
    bshort8 qf = *(const bshort8*)(Q + ((long)(b * L + q0 + qr)) * 512 + h * 32 + g8);

    const u16* src;
    long step;
    char *d0, *d1;
    if (wv < 4) {
        int rk = wv * 16 + (lane >> 2);
        int f = ((rk >> 3) & 3) ^ ((rk >> 1) & 3);
        int sc = (lane & 3) ^ f;
        src = Kb + (long)rk * 512 + sc * 8;
        step = (long)64 * 512;
        d0 = (char*)Ks[0] + wv * 1024;
        d1 = (char*)Ks[1] + wv * 1024;
    } else {
        int rv = (wv - 4) * 8 + (lane >> 3);
        int sc = (lane & 7) ^ (lane >> 3);
        src = Vb + (long)rv * S + sc * 8;
        step = 64;
        d0 = (char*)Vs[0] + (wv - 4) * 1024;
        d1 = (char*)Vs[1] + (wv - 4) * 1024;
    }

    f32x4 acc0 = {}, acc1 = {};
    float lsum = 0.f;
    int f0 = (qr >> 2) ^ ((qr >> 1) & 1);
    int f1 = f0 ^ 2;

    gload_lds16(src, d0);
    int cur = 0;
    for (int t = 0; t < nt; ++t) {
        if (t + 1 < nt) {
            gload_lds16(src + (long)(t + 1) * step, cur ? d0 : d1);
            asm volatile("s_waitcnt vmcnt(1)\ns_barrier" ::: "memory");
        } else {
            asm volatile("s_waitcnt vmcnt(0)\ns_barrier" ::: "memory");
        }
        const char* Kt = (const char*)Ks[cur];
        const char* Vl = (const char*)Vs[cur];
        bshort8 a0 = *(const bshort8*)(Kt + kperm * 64 + ((g ^ f0) << 4));
        bshort8 a1 = *(const bshort8*)(Kt + (kperm + 4) * 64 + ((g ^ f1) << 4));
        bshort8 a2 = *(const bshort8*)(Kt + (kperm + 32) * 64 + ((g ^ f0) << 4));
        bshort8 a3 = *(const bshort8*)(Kt + (kperm + 36) * 64 + ((g ^ f1) << 4));
        bshort8 v00 = *(const bshort8*)(Vl + qr * 128 + ((g ^ (qr & 7)) << 4));
        bshort8 v01 = *(const bshort8*)(Vl + qr * 128 + (((g + 4) ^ (qr & 7)) << 4));
        bshort8 v10 = *(const bshort8*)(Vl + (16 + qr) * 128 + ((g ^ (qr & 7)) << 4));
        bshort8 v11 = *(const bshort8*)(Vl + (16 + qr) * 128 + (((g + 4) ^ (qr & 7)) << 4));
        f32x4 zz = {0.f, 0.f, 0.f, 0.f};
        f32x4 st0 = __builtin_amdgcn_mfma_f32_16x16x32_bf16(a0, qf, zz, 0, 0, 0);
        f32x4 st1 = __builtin_amdgcn_mfma_f32_16x16x32_bf16(a1, qf, zz, 0, 0, 0);
        f32x4 st2 = __builtin_amdgcn_mfma_f32_16x16x32_bf16(a2, qf, zz, 0, 0, 0);
        f32x4 st3 = __builtin_amdgcn_mfma_f32_16x16x32_bf16(a3, qf, zz, 0, 0, 0);
        float p0[4], p1[4], p2[4], p3[4];
        #pragma unroll
        for (int r = 0; r < 4; r++) {
            p0[r] = exp2c(st0[r]);
            p1[r] = exp2c(st1[r]);
            p2[r] = exp2c(st2[r]);
            p3[r] = exp2c(st3[r]);
        }
        float ps = ((p0[0] + p0[1]) + (p0[2] + p0[3])) + ((p1[0] + p1[1]) + (p1[2] + p1[3])) +
                   ((p2[0] + p2[1]) + (p2[2] + p2[3])) + ((p3[0] + p3[1]) + (p3[2] + p3[3]));
        lsum += ps;
        u32x4 P0 = { cvtpk(p0[0], p0[1]), cvtpk(p0[2], p0[3]),
                     cvtpk(p1[0], p1[1]), cvtpk(p1[2], p1[3]) };
        u32x4 P1 = { cvtpk(p2[0], p2[1]), cvtpk(p2[2], p2[3]),
                     cvtpk(p3[0], p3[1]), cvtpk(p3[2], p3[3]) };
        bshort8 pf0 = *(bshort8*)&P0;
        bshort8 pf1 = *(bshort8*)&P1;
        acc0 = __builtin_amdgcn_mfma_f32_16x16x32_bf16(v00, pf0, acc0, 0, 0, 0);
        acc0 = __builtin_amdgcn_mfma_f32_16x16x32_bf16(v01, pf1, acc0, 0, 0, 0);
        acc1 = __builtin_amdgcn_mfma_f32_16x16x32_bf16(v10, pf0, acc1, 0, 0, 0);
        acc1 = __builtin_amdgcn_mfma_f32_16x16x32_bf16(v11, pf1, acc1, 0, 0, 0);
        asm volatile("s_barrier" ::: "memory");
        cur ^= 1;
    }

    lsum += __shfl_xor(lsum, 16);
    lsum += __shfl_xor(lsum, 32);
    float inv = 1.f / lsum;
    u16* op = O + ((long)(b * L + q0 + qr)) * 512 + h * 32 + g * 4;
    sshort4 o0, o1;
    #pragma unroll
    for (int r = 0; r < 4; r++) {
        o0[r] = (short)f2b(acc0[r] * inv);
        o1[r] = (short)f2b(acc1[r] * inv);
    }
    *(sshort4*)op = o0;
    *(sshort4*)(op + 16) = o1;
}

// ---------------- layernorm over 512; fp32 + bf16 dual-store ----------------
__global__ __launch_bounds__(256) void ln_kernel(const float* __restrict__ X,
                                                 const float* __restrict__ g,
                                                 const float* __restrict__ bt,
                                                 float* __restrict__ Y,
                                                 u16* __restrict__ Yb) {
    int row = blockIdx.x;
    const float* xr = X + (long)row * 512;
    int t = threadIdx.x;
    float x0 = xr[t], x1 = xr[t + 256];
    float s = x0 + x1, ss = x0 * x0 + x1 * x1;
    #pragma unroll
    for (int off = 32; off > 0; off >>= 1) {
        s += __shfl_down(s, off);
        ss += __shfl_down(ss, off);
    }
    __shared__ float sred[4], ssred[4];
    int wid = t >> 6;
    if ((t & 63) == 0) { sred[wid] = s; ssred[wid] = ss; }
    __syncthreads();
    float ts = sred[0] + sred[1] + sred[2] + sred[3];
    float tss = ssred[0] + ssred[1] + ssred[2] + ssred[3];
    float mean = ts * (1.f / 512.f);
    float var = tss * (1.f / 512.f) - mean * mean;
    float rstd = rsqrtf(var + 1e-5f);
    float y0 = (x0 - mean) * rstd * g[t] + bt[t];
    float y1 = (x1 - mean) * rstd * g[t + 256] + bt[t + 256];
    Y[(long)row * 512 + t] = y0;
    Y[(long)row * 512 + t + 256] = y1;
    Yb[(long)row * 512 + t] = f2b(y0);
    Yb[(long)row * 512 + t + 256] = f2b(y1);
}

// ---------------- LN3 pass 1: per-row mean/rstd (one wave per row) ----------------
__global__ __launch_bounds__(256) void ln_stats_kernel(const float* __restrict__ X,
                                                       float2* __restrict__ stats) {
    int row = blockIdx.x * 4 + (threadIdx.x >> 6);
    int lane = threadIdx.x & 63;
    const float4* xr = (const float4*)(X + (long)row * 512) + lane * 2;
    float4 a = xr[0], b = xr[1];
    float s = (a.x + a.y) + (a.z + a.w) + (b.x + b.y) + (b.z + b.w);
    float ss = (a.x * a.x + a.y * a.y) + (a.z * a.z + a.w * a.w) +
               (b.x * b.x + b.y * b.y) + (b.z * b.z + b.w * b.w);
    #pragma unroll
    for (int off = 32; off > 0; off >>= 1) {
        s += __shfl_down(s, off);
        ss += __shfl_down(ss, off);
    }
    if (lane == 0) {
        float mean = s * (1.f / 512.f);
        float var = ss * (1.f / 512.f) - mean * mean;
        stats[row] = make_float2(mean, rsqrtf(var + 1e-5f));
    }
}

// ---------------- LN3 pass 2: LDS-tiled transpose + normalize -> [B,512,L] ----------
__global__ __launch_bounds__(256) void ln_trans_kernel(
    const float* __restrict__ X, const float2* __restrict__ stats,
    const float* __restrict__ g, const float* __restrict__ bt,
    float* __restrict__ Y) {
    __shared__ float T[64][65];
    int b = blockIdx.z, l0 = blockIdx.x * 64, c0 = blockIdx.y * 64;
    int t = threadIdx.x;
    int col = t & 63, rq = t >> 6;
    #pragma unroll
    for (int i = 0; i < 16; i++) {
        int row = i * 4 + rq;
        T[row][col] = X[((long)(b * 1024 + l0 + row)) * 512 + c0 + col];
    }
    __syncthreads();
    float2 mr = stats[b * 1024 + l0 + col];
    #pragma unroll
    for (int i = 0; i < 16; i++) {
        int c = i * 4 + rq;
        float val = (T[col][c] - mr.x) * mr.y * g[c0 + c] + bt[c0 + c];
        Y[((long)(b * 512 + c0 + c)) * 1024 + l0 + col] = val;
    }
}

extern "C" void kernel_launch(void* const* d_in, const int* in_sizes, int n_in,
                              void* d_out, int out_size, void* d_ws, size_t ws_size,
                              hipStream_t stream) {
    const float* x      = (const float*)d_in[0];
    const float* gfeat  = (const float*)d_in[1];
    const float* conv_w = (const float*)d_in[2];
    const float* conv_b = (const float*)d_in[3];
    const float* sa_wq = (const float*)d_in[4];
    const float* sa_bq = (const float*)d_in[5];
    const float* sa_wk = (const float*)d_in[6];
    const float* sa_bk = (const float*)d_in[7];
    const float* sa_wv = (const float*)d_in[8];
    const float* sa_bv = (const float*)d_in[9];
    const float* sa_wo = (const float*)d_in[10];
    const float* sa_bo = (const float*)d_in[11];
    const float* ca_wq = (const float*)d_in[12];
    const float* ca_bq = (const float*)d_in[13];
    const float* ca_wk = (const float*)d_in[14];
    const float* ca_bk = (const float*)d_in[15];
    const float* ca_wv = (const float*)d_in[16];
    const float* ca_bv = (const float*)d_in[17];
    const float* ca_wo = (const float*)d_in[18];
    const float* ca_bo = (const float*)d_in[19];
    const float* ffn_w1 = (const float*)d_in[20];
    const float* ffn_b1 = (const float*)d_in[21];
    const float* ffn_w2 = (const float*)d_in[22];
    const float* ffn_b2 = (const float*)d_in[23];
    const float* n1_g = (const float*)d_in[24];
    const float* n1_b = (const float*)d_in[25];
    const float* n2_g = (const float*)d_in[26];
    const float* n2_b = (const float*)d_in[27];
    const float* n3_g = (const float*)d_in[28];
    const float* n3_b = (const float*)d_in[29];
    (void)ws_size; (void)n_in; (void)in_sizes; (void)out_size;

    const long M_ = 1048576;
    float* W0 = (float*)d_ws;
    float* h   = W0;                 // [0, 2M) fp32
    float* hn  = W0 + 2 * M_;        // [2M, 4M) fp32
    u16* U = (u16*)(W0 + 4 * M_);
    u16* qb     = U;                 // 2M u16
    u16* kb     = U + 2 * M_;        // 2M
    u16* vtb    = U + 4 * M_;        // 2M   [4][512][1024]
    u16* k2b    = U + 6 * M_;        // 1M
    u16* v2tb   = U + 7 * M_;        // 1M   [4][512][512]
    u16* attb   = U + 8 * M_;        // 2M
    u16* hnb    = U + 10 * M_;       // 2M
    u16* midb   = U + 12 * M_;       // 8M
    u16* wsb    = U + 20 * M_;       // 6.55M
    u16* res_tb = U + 27 * M_;       // 1M (dead after conv; reused as LN3 stats)
    u16* crossb = U + 28 * M_;       // 1M

    float2* ln3_stats = (float2*)res_tb;

    const u16* conv_wb = wsb;
    const u16* sa_wqb = wsb + 262144;   // wq,wk,wv contiguous -> fused QKV weight
    const u16* sa_wob = wsb + 1048576;
    const u16* ca_wqb = wsb + 1310720;
    const u16* ca_wkb = wsb + 1572864;  // wk,wv contiguous -> fused KV weight
    const u16* ca_wob = wsb + 2097152;
    const u16* ffn1b = wsb + 2359296, *ffn2b = wsb + 3407872;
    const u16* xb = wsb + 4456448;

    // 0. convert weights + x to bf16
    WSrc ws;
    ws.p[0] = conv_w; ws.p[1] = sa_wq; ws.p[2] = sa_wk; ws.p[3] = sa_wv;
    ws.p[4] = sa_wo; ws.p[5] = ca_wq; ws.p[6] = ca_wk; ws.p[7] = ca_wv;
    ws.p[8] = ca_wo; ws.p[9] = ffn_w1; ws.p[10] = ffn_w2; ws.p[11] = x;
    wconv_kernel<<<6400, 256, 0, stream>>>(ws, wsb);

    // 1. window |max-min|+eps, transposed bf16: res_tb [b][n][c]
    win_kernel<<<4096, 256, 0, stream>>>(gfeat, res_tb, 4 * 512 * 512);

    // 2. conv+relu: crossb[b][o][n]  (256 blocks)
    bgemm64_kernel<2, 1, false, 1><<<dim3(8, 8, 4), 256, 0, stream>>>(
        conv_wb, res_tb, conv_b, nullptr, crossb, 512, 512, 512, 0, 262144, 262144,
        nullptr, nullptr, nullptr, nullptr);

    // 3. fused self-attn QKV projection (1536 blocks)
    bgemm64_kernel<1, 0, false, 3><<<dim3(64, 24), 256, 0, stream>>>(
        xb, sa_wqb, sa_bq, nullptr, qb, 4096, 1536, 512, 0, 0, 0,
        kb, vtb, sa_bk, sa_bv);

    // 4. self attention (S=1024), single-pass -> attb bf16
    attn_mfma_kernel<<<dim3(64, 8), 512, 0, stream>>>(qb, kb, vtb, attb, 1024, 1024);

    // 5. out proj + resid x -> h fp32 (512 blocks)
    bgemm64_kernel<1, 0, true, 0><<<dim3(64, 8), 256, 0, stream>>>(
        attb, sa_wob, sa_bo, x, h, 4096, 512, 512, 0, 0, 0,
        nullptr, nullptr, nullptr, nullptr);

    // 6. LN1 -> hn fp32 + hnb bf16
    ln_kernel<<<4096, 256, 0, stream>>>(h, n1_g, n1_b, hn, hnb);

    // 7. cross-attn: Q proj (scaled), fused K2/V2 proj
    bgemm64_kernel<1, 3, false, 1><<<dim3(64, 8), 256, 0, stream>>>(
        hnb, ca_wqb, ca_bq, nullptr, qb, 4096, 512, 512, 0, 0, 0,
        nullptr, nullptr, nullptr, nullptr);
    bgemm64_kernel<1, 0, false, 4><<<dim3(32, 16), 256, 0, stream>>>(
        crossb, ca_wkb, ca_bk, nullptr, k2b, 2048, 1024, 512, 0, 0, 0,
        nullptr, v2tb, ca_bv, nullptr);

    // 8. cross attention (S=512), single-pass -> attb bf16
    attn_mfma_kernel<<<dim3(64, 8), 512, 0, stream>>>(qb, k2b, v2tb, attb, 1024, 512);

    // 9. out proj + resid hn -> h fp32
    bgemm64_kernel<1, 0, true, 0><<<dim3(64, 8), 256, 0, stream>>>(
        attb, ca_wob, ca_bo, hn, h, 4096, 512, 512, 0, 0, 0,
        nullptr, nullptr, nullptr, nullptr);

    // 10. LN2 -> hn fp32 + hnb bf16
    ln_kernel<<<4096, 256, 0, stream>>>(h, n2_g, n2_b, hn, hnb);

    // 11. FFN up + exact gelu -> midb bf16  [4096,2048] (2048 blocks)
    bgemm64_kernel<1, 2, false, 1><<<dim3(64, 32), 256, 0, stream>>>(
        hnb, ffn1b, ffn_b1, nullptr, midb, 4096, 2048, 512, 0, 0, 0,
        nullptr, nullptr, nullptr, nullptr);

    // 12. FFN down + resid hn -> h fp32  [4096,512] K=2048
    bgemm64_kernel<1, 0, true, 0><<<dim3(64, 8), 256, 0, stream>>>(
        midb, ffn2b, ffn_b2, hn, h, 4096, 512, 2048, 0, 0, 0,
        nullptr, nullptr, nullptr, nullptr);

    // 13. LN3: per-row stats, then LDS-tiled transpose -> d_out [B,512,L] fp32
    ln_stats_kernel<<<1024, 256, 0, stream>>>(h, ln3_stats);
    ln_trans_kernel<<<dim3(16, 8, 4), 256, 0, stream>>>(
        h, ln3_stats, n3_g, n3_b, (float*)d_out);
}

// Round 11
// 168.204 us; speedup vs baseline: 1.4775x; 1.0337x over previous
//
#include <hip/hip_runtime.h>
#include <hip/hip_bf16.h>
#include <math.h>

#define SCALE_Q 0.25504522f  // 1/sqrt(32) * log2(e)  (Q pre-scale for exp2 softmax)

typedef unsigned short u16;
typedef unsigned int u32;
typedef __attribute__((ext_vector_type(8))) short bshort8;
typedef __attribute__((ext_vector_type(4))) short sshort4;
typedef __attribute__((ext_vector_type(4))) float f32x4;
typedef __attribute__((ext_vector_type(4))) u32 u32x4;

__device__ inline u16 f2b(float f) {  // fp32 -> bf16 RNE
    union { float f; uint32_t u; } c;
    c.f = f;
    uint32_t u = c.u;
    return (u16)((u + 0x7fffu + ((u >> 16) & 1u)) >> 16);
}

__device__ __forceinline__ u32 cvtpk(float a, float b) {  // {lo=bf16(a), hi=bf16(b)}
    u32 r;
    asm("v_cvt_pk_bf16_f32 %0, %1, %2" : "=v"(r) : "v"(a), "v"(b));
    return r;
}

__device__ __forceinline__ float exp2c(float s) {  // 2^min(s,100)
    float c = fminf(s, 100.f);
    float r;
    asm("v_exp_f32 %0, %1" : "=v"(r) : "v"(c));
    return r;
}

__device__ inline void gload_lds16(const void* g, void* lds) {
    __builtin_amdgcn_global_load_lds(
        (const __attribute__((address_space(1))) void*)g,
        (__attribute__((address_space(3))) void*)lds, 16, 0, 0);
}

// ---------------- fused prep: bf16 convert (weights+x) AND window-reduce ----------
// blocks [0,256): window |max-min|+eps on gfeat -> res_tb [b][n][c] bf16, via
//   LDS-tiled transpose (coalesced reads AND writes).
// blocks [256,6656): fp32->bf16 convert of 11 weights + x.
struct WSrc { const float* p[12]; };
__global__ __launch_bounds__(256) void prep_kernel(WSrc s, u16* __restrict__ dst,
                                                   const float* __restrict__ G,
                                                   u16* __restrict__ Rt) {
    int bid = blockIdx.x;
    if (bid < 256) {
        __shared__ u16 T[64][72];  // row stride 144B (16B-aligned)
        int b = bid >> 6, c0 = ((bid >> 3) & 7) << 6, n0 = (bid & 7) << 6;
        int t = threadIdx.x;
        int n = t & 63, cq = t >> 6;
        const float* Gb = G + (long)b * 512 * 4096;
        #pragma unroll
        for (int i = 0; i < 16; i++) {
            int c = i * 4 + cq;
            const float4* p = (const float4*)(Gb + (long)(c0 + c) * 4096 + (n0 + n) * 8);
            float4 a = p[0], bb = p[1];
            float mx = fmaxf(fmaxf(fmaxf(a.x, a.y), fmaxf(a.z, a.w)),
                             fmaxf(fmaxf(bb.x, bb.y), fmaxf(bb.z, bb.w)));
            float mn = fminf(fminf(fminf(a.x, a.y), fminf(a.z, a.w)),
                             fminf(fminf(bb.x, bb.y), fminf(bb.z, bb.w)));
            T[n][c] = f2b(fabsf(mx - mn) + 1e-6f);
        }
        __syncthreads();
        int nr = t >> 2, ck = (t & 3) << 4;
        u16* o = Rt + ((long)(b * 512 + n0 + nr) << 9) + c0 + ck;
        *(bshort8*)o = *(const bshort8*)&T[nr][ck];
        *(bshort8*)(o + 8) = *(const bshort8*)&T[nr][ck + 8];
    } else {
        long e = ((long)(bid - 256) * 256 + threadIdx.x) * 4;
        if (e >= 6553600) return;
        int w; long base;
        if (e < 2359296)      { w = (int)(e >> 18); base = (long)w << 18; }
        else if (e < 3407872) { w = 9;  base = 2359296; }
        else if (e < 4456448) { w = 10; base = 3407872; }
        else                  { w = 11; base = 4456448; }
        float4 v = *(const float4*)(s.p[w] + (e - base));
        dst[e + 0] = f2b(v.x); dst[e + 1] = f2b(v.y);
        dst[e + 2] = f2b(v.z); dst[e + 3] = f2b(v.w);
    }
}

// ================= shared epilogue =================
template <int BIASMODE, int ACT, bool RESID, int OUTMODE>
__device__ __forceinline__ void gemm_epilogue_elem(
    float v, int row, int col, int N, long zoff,
    const float* bias, const float* Rres, void* Cout,
    u16* D1, u16* D2, const float* bias1, const float* bias2) {
    if (OUTMODE == 3) {  // fused QKV split
        int grp = col >> 9, c = col & 511;
        float bb = (grp == 0) ? bias[c] : (grp == 1) ? bias1[c] : bias2[c];
        float vv = v + bb;
        if (grp == 0)
            ((u16*)Cout)[(long)row * 512 + c] = f2b(vv * SCALE_Q);
        else if (grp == 1)
            D1[(long)row * 512 + c] = f2b(vv);
        else
            D2[((long)((row >> 10) * 512 + c) << 10) + (row & 1023)] = f2b(vv);
    } else if (OUTMODE == 4) {  // fused KV split
        int grp = col >> 9, c = col & 511;
        float vv = v + ((grp == 0) ? bias[c] : bias1[c]);
        if (grp == 0)
            ((u16*)Cout)[(long)row * 512 + c] = f2b(vv);
        else
            D2[((long)((row >> 9) * 512 + c) << 9) + (row & 511)] = f2b(vv);
    } else {
        if (BIASMODE == 1) v += bias[col];
        if (BIASMODE == 2) v += bias[row];
        if (ACT == 1) v = fmaxf(v, 0.f);
        if (ACT == 2) v = 0.5f * v * (1.f + erff(v * 0.70710678118654752f));
        if (ACT == 3) v *= SCALE_Q;
        if (RESID) v += Rres[(long)row * N + col];
        long off = zoff + (long)row * N + col;
        if (OUTMODE == 1) ((u16*)Cout)[off] = f2b(v);
        else              ((float*)Cout)[off] = v;
    }
}

// ---------------- bf16 MFMA GEMM, 64x64 tile, double-buffered counted-vmcnt ---------
template <int BIASMODE, int ACT, bool RESID, int OUTMODE>
__global__ __launch_bounds__(256) void bgemm64_kernel(
    const u16* __restrict__ A, const u16* __restrict__ Bt,
    const float* __restrict__ bias, const float* __restrict__ Rres,
    void* __restrict__ Cout, int M, int N, int K,
    long sA, long sB, long sC,
    u16* __restrict__ D1, u16* __restrict__ D2,
    const float* __restrict__ bias1, const float* __restrict__ bias2) {
    A  += (long)blockIdx.z * sA;
    Bt += (long)blockIdx.z * sB;
    __shared__ u16 As[2][64 * 64];
    __shared__ u16 Bs[2][64 * 64];
    int tid = threadIdx.x;
    int lane = tid & 63, wv = tid >> 6;
    int wr = wv >> 1, wc = wv & 1;
    int m0 = blockIdx.x * 64, n0 = blockIdx.y * 64;
    f32x4 acc[2][2] = {};
    int srow = lane >> 3;
    int selem = ((lane & 7) ^ srow) << 3;

    auto STAGE = [&](int buf, int k0) {
        #pragma unroll
        for (int i = 0; i < 2; i++) {
            int roff = i * 32 + wv * 8;
            gload_lds16(A + (long)(m0 + roff + srow) * K + k0 + selem,
                        (char*)As[buf] + roff * 128);
            gload_lds16(Bt + (long)(n0 + roff + srow) * K + k0 + selem,
                        (char*)Bs[buf] + roff * 128);
        }
    };

    int NT = K >> 6;
    STAGE(0, 0);
    int cur = 0;
    for (int kt = 0; kt < NT; ++kt) {
        if (kt + 1 < NT) {
            STAGE(cur ^ 1, (kt + 1) << 6);
            asm volatile("s_waitcnt vmcnt(4)\ns_barrier" ::: "memory");
        } else {
            asm volatile("s_waitcnt vmcnt(0)\ns_barrier" ::: "memory");
        }
        #pragma unroll
        for (int ks = 0; ks < 2; ks++) {
            bshort8 af[2], bf[2];
            int kbo = ks * 64 + ((lane >> 4) << 4);
            #pragma unroll
            for (int f = 0; f < 2; f++) {
                int arow = wr * 32 + f * 16 + (lane & 15);
                af[f] = *(const bshort8*)((const char*)As[cur] + arow * 128 +
                                          (kbo ^ ((arow & 7) << 4)));
                int brow = wc * 32 + f * 16 + (lane & 15);
                bf[f] = *(const bshort8*)((const char*)Bs[cur] + brow * 128 +
                                          (kbo ^ ((brow & 7) << 4)));
            }
            #pragma unroll
            for (int fi = 0; fi < 2; fi++)
                #pragma unroll
                for (int fj = 0; fj < 2; fj++)
                    acc[fi][fj] = __builtin_amdgcn_mfma_f32_16x16x32_bf16(
                        af[fi], bf[fj], acc[fi][fj], 0, 0, 0);
        }
        asm volatile("s_barrier" ::: "memory");
        cur ^= 1;
    }
    long zoff = (long)blockIdx.z * sC;
    #pragma unroll
    for (int fi = 0; fi < 2; fi++)
        #pragma unroll
        for (int fj = 0; fj < 2; fj++)
            #pragma unroll
            for (int r = 0; r < 4; r++) {
                int row = m0 + wr * 32 + fi * 16 + ((lane >> 4) << 2) + r;
                int col = n0 + wc * 32 + fj * 16 + (lane & 15);
                gemm_epilogue_elem<BIASMODE, ACT, RESID, OUTMODE>(
                    acc[fi][fj][r], row, col, N, zoff, bias, Rres, Cout,
                    D1, D2, bias1, bias2);
            }
}

// ---------------- fused MFMA flash attention: 8 waves, triple-buffered ----------
// Q [B,L,512] bf16 (pre-scaled), K [B,S,512] bf16, Vt [B,512,S] bf16, O bf16.
// Grid (bh=64, L/128), 512 threads. Depth-2 prefetch: 3 LDS buffers, issue tile
// t+2, s_waitcnt vmcnt(2). lsum via ones-MFMA third accumulator (no VALU adds,
// no final shuffle). No-max exp2 softmax (Q pre-scaled by log2e).
__global__ __launch_bounds__(512) void attn_mfma_kernel(
    const u16* __restrict__ Q, const u16* __restrict__ K,
    const u16* __restrict__ Vt, u16* __restrict__ O, int L, int S) {
    __shared__ __align__(16) u16 Ks[3][2048];
    __shared__ __align__(16) u16 Vs[3][2048];
    int bh = blockIdx.x;
    int b = bh >> 4, h = bh & 15;
    int tid = threadIdx.x;
    int lane = tid & 63, wv = tid >> 6;
    int q0 = blockIdx.y * 128 + wv * 16;
    int qr = lane & 15, g = lane >> 4, g8 = g * 8;
    int kperm = 8 * (qr >> 2) + (qr & 3);
    int nt = S >> 6;

    const u16* Kb = K + (long)b * S * 512 + h * 32;
    const u16* Vb = Vt + ((long)b * 512 + h * 32) * S;
    bshort8 qf = *(const bshort8*)(Q + ((long)(b * L + q0 + qr)) * 512 + h * 32 + g8);

    const u16* src;
    long step;
    char* d0;
    if (wv < 4) {
        int rk = wv * 16 + (lane >> 2);
        int f = ((rk >> 3) & 3) ^ ((rk >> 1) & 3);
        int sc = (lane & 3) ^ f;
        src = Kb + (long)rk * 512 + sc * 8;
        step = (long)64 * 512;
        d0 = (char*)Ks[0] + wv * 1024;
    } else {
        int rv = (wv - 4) * 8 + (lane >> 3);
        int sc = (lane & 7) ^ (lane >> 3);
        src = Vb + (long)rv * S + sc * 8;
        step = 64;
        d0 = (char*)Vs[0] + (wv - 4) * 1024;
    }

    f32x4 acc0 = {}, acc1 = {}, acc2 = {};
    const bshort8 onesf = { (short)0x3F80, (short)0x3F80, (short)0x3F80, (short)0x3F80,
                            (short)0x3F80, (short)0x3F80, (short)0x3F80, (short)0x3F80 };
    int f0 = (qr >> 2) ^ ((qr >> 1) & 1);
    int f1 = f0 ^ 2;

    gload_lds16(src, d0);
    gload_lds16(src + step, d0 + 4096);
    int cur = 0;
    for (int t = 0; t < nt; ++t) {
        if (t + 2 < nt) {
            int nb = cur + 2; if (nb >= 3) nb -= 3;
            gload_lds16(src + (long)(t + 2) * step, d0 + nb * 4096);
            asm volatile("s_waitcnt vmcnt(2)\ns_barrier" ::: "memory");
        } else if (t + 1 < nt) {
            asm volatile("s_waitcnt vmcnt(1)\ns_barrier" ::: "memory");
        } else {
            asm volatile("s_waitcnt vmcnt(0)\ns_barrier" ::: "memory");
        }
        const char* Kt = (const char*)Ks[0] + cur * 4096;
        const char* Vl = (const char*)Vs[0] + cur * 4096;
        bshort8 a0 = *(const bshort8*)(Kt + kperm * 64 + ((g ^ f0) << 4));
        bshort8 a1 = *(const bshort8*)(Kt + (kperm + 4) * 64 + ((g ^ f1) << 4));
        bshort8 a2 = *(const bshort8*)(Kt + (kperm + 32) * 64 + ((g ^ f0) << 4));
        bshort8 a3 = *(const bshort8*)(Kt + (kperm + 36) * 64 + ((g ^ f1) << 4));
        bshort8 v00 = *(const bshort8*)(Vl + qr * 128 + ((g ^ (qr & 7)) << 4));
        bshort8 v01 = *(const bshort8*)(Vl + qr * 128 + (((g + 4) ^ (qr & 7)) << 4));
        bshort8 v10 = *(const bshort8*)(Vl + (16 + qr) * 128 + ((g ^ (qr & 7)) << 4));
        bshort8 v11 = *(const bshort8*)(Vl + (16 + qr) * 128 + (((g + 4) ^ (qr & 7)) << 4));
        f32x4 zz = {0.f, 0.f, 0.f, 0.f};
        f32x4 st0 = __builtin_amdgcn_mfma_f32_16x16x32_bf16(a0, qf, zz, 0, 0, 0);
        f32x4 st1 = __builtin_amdgcn_mfma_f32_16x16x32_bf16(a1, qf, zz, 0, 0, 0);
        f32x4 st2 = __builtin_amdgcn_mfma_f32_16x16x32_bf16(a2, qf, zz, 0, 0, 0);
        f32x4 st3 = __builtin_amdgcn_mfma_f32_16x16x32_bf16(a3, qf, zz, 0, 0, 0);
        float p0[4], p1[4], p2[4], p3[4];
        #pragma unroll
        for (int r = 0; r < 4; r++) {
            p0[r] = exp2c(st0[r]);
            p1[r] = exp2c(st1[r]);
            p2[r] = exp2c(st2[r]);
            p3[r] = exp2c(st3[r]);
        }
        u32x4 P0 = { cvtpk(p0[0], p0[1]), cvtpk(p0[2], p0[3]),
                     cvtpk(p1[0], p1[1]), cvtpk(p1[2], p1[3]) };
        u32x4 P1 = { cvtpk(p2[0], p2[1]), cvtpk(p2[2], p2[3]),
                     cvtpk(p3[0], p3[1]), cvtpk(p3[2], p3[3]) };
        bshort8 pf0 = *(bshort8*)&P0;
        bshort8 pf1 = *(bshort8*)&P1;
        acc0 = __builtin_amdgcn_mfma_f32_16x16x32_bf16(v00, pf0, acc0, 0, 0, 0);
        acc0 = __builtin_amdgcn_mfma_f32_16x16x32_bf16(v01, pf1, acc0, 0, 0, 0);
        acc1 = __builtin_amdgcn_mfma_f32_16x16x32_bf16(v10, pf0, acc1, 0, 0, 0);
        acc1 = __builtin_amdgcn_mfma_f32_16x16x32_bf16(v11, pf1, acc1, 0, 0, 0);
        acc2 = __builtin_amdgcn_mfma_f32_16x16x32_bf16(onesf, pf0, acc2, 0, 0, 0);
        acc2 = __builtin_amdgcn_mfma_f32_16x16x32_bf16(onesf, pf1, acc2, 0, 0, 0);
        asm volatile("s_barrier" ::: "memory");
        cur = (cur == 2) ? 0 : cur + 1;
    }

    float inv = 1.f / acc2[0];  // every row of the ones-MFMA output = lsum(qr)
    u16* op = O + ((long)(b * L + q0 + qr)) * 512 + h * 32 + g * 4;
    sshort4 o0, o1;
    #pragma unroll
    for (int r = 0; r < 4; r++) {
        o0[r] = (short)f2b(acc0[r] * inv);
        o1[r] = (short)f2b(acc1[r] * inv);
    }
    *(sshort4*)op = o0;
    *(sshort4*)(op + 16) = o1;
}

// ---------------- layernorm over 512; fp32 + bf16 dual-store ----------------
__global__ __launch_bounds__(256) void ln_kernel(const float* __restrict__ X,
                                                 const float* __restrict__ g,
                                                 const float* __restrict__ bt,
                                                 float* __restrict__ Y,
                                                 u16* __restrict__ Yb) {
    int row = blockIdx.x;
    const float* xr = X + (long)row * 512;
    int t = threadIdx.x;
    float x0 = xr[t], x1 = xr[t + 256];
    float s = x0 + x1, ss = x0 * x0 + x1 * x1;
    #pragma unroll
    for (int off = 32; off > 0; off >>= 1) {
        s += __shfl_down(s, off);
        ss += __shfl_down(ss, off);
    }
    __shared__ float sred[4], ssred[4];
    int wid = t >> 6;
    if ((t & 63) == 0) { sred[wid] = s; ssred[wid] = ss; }
    __syncthreads();
    float ts = sred[0] + sred[1] + sred[2] + sred[3];
    float tss = ssred[0] + ssred[1] + ssred[2] + ssred[3];
    float mean = ts * (1.f / 512.f);
    float var = tss * (1.f / 512.f) - mean * mean;
    float rstd = rsqrtf(var + 1e-5f);
    float y0 = (x0 - mean) * rstd * g[t] + bt[t];
    float y1 = (x1 - mean) * rstd * g[t + 256] + bt[t + 256];
    Y[(long)row * 512 + t] = y0;
    Y[(long)row * 512 + t + 256] = y1;
    Yb[(long)row * 512 + t] = f2b(y0);
    Yb[(long)row * 512 + t + 256] = f2b(y1);
}

// ---------------- LN3 pass 1: per-row mean/rstd (one wave per row) ----------------
__global__ __launch_bounds__(256) void ln_stats_kernel(const float* __restrict__ X,
                                                       float2* __restrict__ stats) {
    int row = blockIdx.x * 4 + (threadIdx.x >> 6);
    int lane = threadIdx.x & 63;
    const float4* xr = (const float4*)(X + (long)row * 512) + lane * 2;
    float4 a = xr[0], b = xr[1];
    float s = (a.x + a.y) + (a.z + a.w) + (b.x + b.y) + (b.z + b.w);
    float ss = (a.x * a.x + a.y * a.y) + (a.z * a.z + a.w * a.w) +
               (b.x * b.x + b.y * b.y) + (b.z * b.z + b.w * b.w);
    #pragma unroll
    for (int off = 32; off > 0; off >>= 1) {
        s += __shfl_down(s, off);
        ss += __shfl_down(ss, off);
    }
    if (lane == 0) {
        float mean = s * (1.f / 512.f);
        float var = ss * (1.f / 512.f) - mean * mean;
        stats[row] = make_float2(mean, rsqrtf(var + 1e-5f));
    }
}

// ---------------- LN3 pass 2: LDS-tiled transpose + normalize -> [B,512,L] ----------
__global__ __launch_bounds__(256) void ln_trans_kernel(
    const float* __restrict__ X, const float2* __restrict__ stats,
    const float* __restrict__ g, const float* __restrict__ bt,
    float* __restrict__ Y) {
    __shared__ float T[64][65];
    int b = blockIdx.z, l0 = blockIdx.x * 64, c0 = blockIdx.y * 64;
    int t = threadIdx.x;
    int col = t & 63, rq = t >> 6;
    #pragma unroll
    for (int i = 0; i < 16; i++) {
        int row = i * 4 + rq;
        T[row][col] = X[((long)(b * 1024 + l0 + row)) * 512 + c0 + col];
    }
    __syncthreads();
    float2 mr = stats[b * 1024 + l0 + col];
    #pragma unroll
    for (int i = 0; i < 16; i++) {
        int c = i * 4 + rq;
        float val = (T[col][c] - mr.x) * mr.y * g[c0 + c] + bt[c0 + c];
        Y[((long)(b * 512 + c0 + c)) * 1024 + l0 + col] = val;
    }
}

extern "C" void kernel_launch(void* const* d_in, const int* in_sizes, int n_in,
                              void* d_out, int out_size, void* d_ws, size_t ws_size,
                              hipStream_t stream) {
    const float* x      = (const float*)d_in[0];
    const float* gfeat  = (const float*)d_in[1];
    const float* conv_w = (const float*)d_in[2];
    const float* conv_b = (const float*)d_in[3];
    const float* sa_wq = (const float*)d_in[4];
    const float* sa_bq = (const float*)d_in[5];
    const float* sa_wk = (const float*)d_in[6];
    const float* sa_bk = (const float*)d_in[7];
    const float* sa_wv = (const float*)d_in[8];
    const float* sa_bv = (const float*)d_in[9];
    const float* sa_wo = (const float*)d_in[10];
    const float* sa_bo = (const float*)d_in[11];
    const float* ca_wq = (const float*)d_in[12];
    const float* ca_bq = (const float*)d_in[13];
    const float* ca_wk = (const float*)d_in[14];
    const float* ca_bk = (const float*)d_in[15];
    const float* ca_wv = (const float*)d_in[16];
    const float* ca_bv = (const float*)d_in[17];
    const float* ca_wo = (const float*)d_in[18];
    const float* ca_bo = (const float*)d_in[19];
    const float* ffn_w1 = (const float*)d_in[20];
    const float* ffn_b1 = (const float*)d_in[21];
    const float* ffn_w2 = (const float*)d_in[22];
    const float* ffn_b2 = (const float*)d_in[23];
    const float* n1_g = (const float*)d_in[24];
    const float* n1_b = (const float*)d_in[25];
    const float* n2_g = (const float*)d_in[26];
    const float* n2_b = (const float*)d_in[27];
    const float* n3_g = (const float*)d_in[28];
    const float* n3_b = (const float*)d_in[29];
    (void)ws_size; (void)n_in; (void)in_sizes; (void)out_size;

    const long M_ = 1048576;
    float* W0 = (float*)d_ws;
    float* h   = W0;                 // [0, 2M) fp32
    float* hn  = W0 + 2 * M_;        // [2M, 4M) fp32
    u16* U = (u16*)(W0 + 4 * M_);
    u16* qb     = U;                 // 2M u16
    u16* kb     = U + 2 * M_;        // 2M
    u16* vtb    = U + 4 * M_;        // 2M   [4][512][1024]
    u16* k2b    = U + 6 * M_;        // 1M
    u16* v2tb   = U + 7 * M_;        // 1M   [4][512][512]
    u16* attb   = U + 8 * M_;        // 2M
    u16* hnb    = U + 10 * M_;       // 2M
    u16* midb   = U + 12 * M_;       // 8M
    u16* wsb    = U + 20 * M_;       // 6.55M
    u16* res_tb = U + 27 * M_;       // 1M (dead after conv; reused as LN3 stats)
    u16* crossb = U + 28 * M_;       // 1M

    float2* ln3_stats = (float2*)res_tb;

    const u16* conv_wb = wsb;
    const u16* sa_wqb = wsb + 262144;   // wq,wk,wv contiguous -> fused QKV weight
    const u16* sa_wob = wsb + 1048576;
    const u16* ca_wqb = wsb + 1310720;
    const u16* ca_wkb = wsb + 1572864;  // wk,wv contiguous -> fused KV weight
    const u16* ca_wob = wsb + 2097152;
    const u16* ffn1b = wsb + 2359296, *ffn2b = wsb + 3407872;
    const u16* xb = wsb + 4456448;

    // 0+1. fused: weights+x -> bf16 AND window reduce -> res_tb [b][n][c]
    WSrc ws;
    ws.p[0] = conv_w; ws.p[1] = sa_wq; ws.p[2] = sa_wk; ws.p[3] = sa_wv;
    ws.p[4] = sa_wo; ws.p[5] = ca_wq; ws.p[6] = ca_wk; ws.p[7] = ca_wv;
    ws.p[8] = ca_wo; ws.p[9] = ffn_w1; ws.p[10] = ffn_w2; ws.p[11] = x;
    prep_kernel<<<6656, 256, 0, stream>>>(ws, wsb, gfeat, res_tb);

    // 2. conv+relu: crossb[b][o][n]  (256 blocks)
    bgemm64_kernel<2, 1, false, 1><<<dim3(8, 8, 4), 256, 0, stream>>>(
        conv_wb, res_tb, conv_b, nullptr, crossb, 512, 512, 512, 0, 262144, 262144,
        nullptr, nullptr, nullptr, nullptr);

    // 3. fused self-attn QKV projection (1536 blocks)
    bgemm64_kernel<1, 0, false, 3><<<dim3(64, 24), 256, 0, stream>>>(
        xb, sa_wqb, sa_bq, nullptr, qb, 4096, 1536, 512, 0, 0, 0,
        kb, vtb, sa_bk, sa_bv);

    // 4. self attention (S=1024), single-pass -> attb bf16
    attn_mfma_kernel<<<dim3(64, 8), 512, 0, stream>>>(qb, kb, vtb, attb, 1024, 1024);

    // 5. out proj + resid x -> h fp32 (512 blocks)
    bgemm64_kernel<1, 0, true, 0><<<dim3(64, 8), 256, 0, stream>>>(
        attb, sa_wob, sa_bo, x, h, 4096, 512, 512, 0, 0, 0,
        nullptr, nullptr, nullptr, nullptr);

    // 6. LN1 -> hn fp32 + hnb bf16
    ln_kernel<<<4096, 256, 0, stream>>>(h, n1_g, n1_b, hn, hnb);

    // 7. cross-attn: Q proj (scaled), fused K2/V2 proj
    bgemm64_kernel<1, 3, false, 1><<<dim3(64, 8), 256, 0, stream>>>(
        hnb, ca_wqb, ca_bq, nullptr, qb, 4096, 512, 512, 0, 0, 0,
        nullptr, nullptr, nullptr, nullptr);
    bgemm64_kernel<1, 0, false, 4><<<dim3(32, 16), 256, 0, stream>>>(
        crossb, ca_wkb, ca_bk, nullptr, k2b, 2048, 1024, 512, 0, 0, 0,
        nullptr, v2tb, ca_bv, nullptr);

    // 8. cross attention (S=512), single-pass -> attb bf16
    attn_mfma_kernel<<<dim3(64, 8), 512, 0, stream>>>(qb, k2b, v2tb, attb, 1024, 512);

    // 9. out proj + resid hn -> h fp32
    bgemm64_kernel<1, 0, true, 0><<<dim3(64, 8), 256, 0, stream>>>(
        attb, ca_wob, ca_bo, hn, h, 4096, 512, 512, 0, 0, 0,
        nullptr, nullptr, nullptr, nullptr);

    // 10. LN2 -> hn fp32 + hnb bf16
    ln_kernel<<<4096, 256, 0, stream>>>(h, n2_g, n2_b, hn, hnb);

    // 11. FFN up + exact gelu -> midb bf16  [4096,2048] (2048 blocks)
    bgemm64_kernel<1, 2, false, 1><<<dim3(64, 32), 256, 0, stream>>>(
        hnb, ffn1b, ffn_b1, nullptr, midb, 4096, 2048, 512, 0, 0, 0,
        nullptr, nullptr, nullptr, nullptr);

    // 12. FFN down + resid hn -> h fp32  [4096,512] K=2048
    bgemm64_kernel<1, 0, true, 0><<<dim3(64, 8), 256, 0, stream>>>(
        midb, ffn2b, ffn_b2, hn, h, 4096, 512, 2048, 0, 0, 0,
        nullptr, nullptr, nullptr, nullptr);

    // 13. LN3: per-row stats, then LDS-tiled transpose -> d_out [B,512,L] fp32
    ln_stats_kernel<<<1024, 256, 0, stream>>>(h, ln3_stats);
    ln_trans_kernel<<<dim3(16, 8, 4), 256, 0, stream>>>(
        h, ln3_stats, n3_g, n3_b, (float*)d_out);
}

// Round 12
// 165.223 us; speedup vs baseline: 1.5042x; 1.0180x over previous
//
#include <hip/hip_runtime.h>
#include <hip/hip_bf16.h>
#include <math.h>

#define SCALE_Q 0.25504522f  // 1/sqrt(32) * log2(e)  (Q pre-scale for exp2 softmax)

typedef unsigned short u16;
typedef unsigned int u32;
typedef __attribute__((ext_vector_type(8))) short bshort8;
typedef __attribute__((ext_vector_type(4))) short sshort4;
typedef __attribute__((ext_vector_type(4))) float f32x4;
typedef __attribute__((ext_vector_type(4))) u32 u32x4;

__device__ inline u16 f2b(float f) {  // fp32 -> bf16 RNE
    union { float f; uint32_t u; } c;
    c.f = f;
    uint32_t u = c.u;
    return (u16)((u + 0x7fffu + ((u >> 16) & 1u)) >> 16);
}

__device__ __forceinline__ u32 cvtpk(float a, float b) {  // {lo=bf16(a), hi=bf16(b)}
    u32 r;
    asm("v_cvt_pk_bf16_f32 %0, %1, %2" : "=v"(r) : "v"(a), "v"(b));
    return r;
}

__device__ __forceinline__ float exp2c(float s) {  // 2^min(s,100)
    float c = fminf(s, 100.f);
    float r;
    asm("v_exp_f32 %0, %1" : "=v"(r) : "v"(c));
    return r;
}

__device__ inline void gload_lds16(const void* g, void* lds) {
    __builtin_amdgcn_global_load_lds(
        (const __attribute__((address_space(1))) void*)g,
        (__attribute__((address_space(3))) void*)lds, 16, 0, 0);
}

// ---------------- fused prep: bf16 convert (weights+x) AND window-reduce ----------
struct WSrc { const float* p[12]; };
__global__ __launch_bounds__(256) void prep_kernel(WSrc s, u16* __restrict__ dst,
                                                   const float* __restrict__ G,
                                                   u16* __restrict__ Rt) {
    int bid = blockIdx.x;
    if (bid < 256) {
        __shared__ u16 T[64][72];  // row stride 144B (16B-aligned)
        int b = bid >> 6, c0 = ((bid >> 3) & 7) << 6, n0 = (bid & 7) << 6;
        int t = threadIdx.x;
        int n = t & 63, cq = t >> 6;
        const float* Gb = G + (long)b * 512 * 4096;
        #pragma unroll
        for (int i = 0; i < 16; i++) {
            int c = i * 4 + cq;
            const float4* p = (const float4*)(Gb + (long)(c0 + c) * 4096 + (n0 + n) * 8);
            float4 a = p[0], bb = p[1];
            float mx = fmaxf(fmaxf(fmaxf(a.x, a.y), fmaxf(a.z, a.w)),
                             fmaxf(fmaxf(bb.x, bb.y), fmaxf(bb.z, bb.w)));
            float mn = fminf(fminf(fminf(a.x, a.y), fminf(a.z, a.w)),
                             fminf(fminf(bb.x, bb.y), fminf(bb.z, bb.w)));
            T[n][c] = f2b(fabsf(mx - mn) + 1e-6f);
        }
        __syncthreads();
        int nr = t >> 2, ck = (t & 3) << 4;
        u16* o = Rt + ((long)(b * 512 + n0 + nr) << 9) + c0 + ck;
        *(bshort8*)o = *(const bshort8*)&T[nr][ck];
        *(bshort8*)(o + 8) = *(const bshort8*)&T[nr][ck + 8];
    } else {
        long e = ((long)(bid - 256) * 256 + threadIdx.x) * 4;
        if (e >= 6553600) return;
        int w; long base;
        if (e < 2359296)      { w = (int)(e >> 18); base = (long)w << 18; }
        else if (e < 3407872) { w = 9;  base = 2359296; }
        else if (e < 4456448) { w = 10; base = 3407872; }
        else                  { w = 11; base = 4456448; }
        float4 v = *(const float4*)(s.p[w] + (e - base));
        dst[e + 0] = f2b(v.x); dst[e + 1] = f2b(v.y);
        dst[e + 2] = f2b(v.z); dst[e + 3] = f2b(v.w);
    }
}

// ================= GEMM arg bundle =================
struct GArg {
    const u16* A; const u16* Bt;
    const float* bias; const float* Rres;
    void* Cout;
    int N, K;
    long sA, sB, sC;
    u16* D1; u16* D2;
    const float* bias1; const float* bias2;
    int gx, gy;  // grid decode for pair dispatch
};

// ================= shared epilogue =================
template <int BIASMODE, int ACT, bool RESID, int OUTMODE>
__device__ __forceinline__ void gemm_epilogue_elem(
    float v, int row, int col, int N, long zoff,
    const float* bias, const float* Rres, void* Cout,
    u16* D1, u16* D2, const float* bias1, const float* bias2) {
    if (OUTMODE == 3) {  // fused QKV split
        int grp = col >> 9, c = col & 511;
        float bb = (grp == 0) ? bias[c] : (grp == 1) ? bias1[c] : bias2[c];
        float vv = v + bb;
        if (grp == 0)
            ((u16*)Cout)[(long)row * 512 + c] = f2b(vv * SCALE_Q);
        else if (grp == 1)
            D1[(long)row * 512 + c] = f2b(vv);
        else
            D2[((long)((row >> 10) * 512 + c) << 10) + (row & 1023)] = f2b(vv);
    } else if (OUTMODE == 4) {  // fused KV split
        int grp = col >> 9, c = col & 511;
        float vv = v + ((grp == 0) ? bias[c] : bias1[c]);
        if (grp == 0)
            ((u16*)Cout)[(long)row * 512 + c] = f2b(vv);
        else
            D2[((long)((row >> 9) * 512 + c) << 9) + (row & 511)] = f2b(vv);
    } else {
        if (BIASMODE == 1) v += bias[col];
        if (BIASMODE == 2) v += bias[row];
        if (ACT == 1) v = fmaxf(v, 0.f);
        if (ACT == 2) v = 0.5f * v * (1.f + erff(v * 0.70710678118654752f));
        if (ACT == 3) v *= SCALE_Q;
        if (RESID) v += Rres[(long)row * N + col];
        long off = zoff + (long)row * N + col;
        if (OUTMODE == 1) ((u16*)Cout)[off] = f2b(v);
        else              ((float*)Cout)[off] = v;
    }
}

// ---------------- bf16 MFMA GEMM body, 64x64 tile, dbuf counted-vmcnt ----------
template <int BIASMODE, int ACT, bool RESID, int OUTMODE>
__device__ __forceinline__ void bgemm64_body(
    u16* AsB, u16* BsB, const GArg& ga, int bx, int by, int bz) {
    const u16* A  = ga.A + (long)bz * ga.sA;
    const u16* Bt = ga.Bt + (long)bz * ga.sB;
    int K = ga.K, N = ga.N;
    int tid = threadIdx.x;
    int lane = tid & 63, wv = tid >> 6;
    int wr = wv >> 1, wc = wv & 1;
    int m0 = bx * 64, n0 = by * 64;
    f32x4 acc[2][2] = {};
    int srow = lane >> 3;
    int selem = ((lane & 7) ^ srow) << 3;

    auto STAGE = [&](int buf, int k0) {
        #pragma unroll
        for (int i = 0; i < 2; i++) {
            int roff = i * 32 + wv * 8;
            gload_lds16(A + (long)(m0 + roff + srow) * K + k0 + selem,
                        (char*)(AsB + buf * 4096) + roff * 128);
            gload_lds16(Bt + (long)(n0 + roff + srow) * K + k0 + selem,
                        (char*)(BsB + buf * 4096) + roff * 128);
        }
    };

    int NT = K >> 6;
    STAGE(0, 0);
    int cur = 0;
    for (int kt = 0; kt < NT; ++kt) {
        if (kt + 1 < NT) {
            STAGE(cur ^ 1, (kt + 1) << 6);
            asm volatile("s_waitcnt vmcnt(4)\ns_barrier" ::: "memory");
        } else {
            asm volatile("s_waitcnt vmcnt(0)\ns_barrier" ::: "memory");
        }
        const char* Asc = (const char*)(AsB + cur * 4096);
        const char* Bsc = (const char*)(BsB + cur * 4096);
        #pragma unroll
        for (int ks = 0; ks < 2; ks++) {
            bshort8 af[2], bf[2];
            int kbo = ks * 64 + ((lane >> 4) << 4);
            #pragma unroll
            for (int f = 0; f < 2; f++) {
                int arow = wr * 32 + f * 16 + (lane & 15);
                af[f] = *(const bshort8*)(Asc + arow * 128 + (kbo ^ ((arow & 7) << 4)));
                int brow = wc * 32 + f * 16 + (lane & 15);
                bf[f] = *(const bshort8*)(Bsc + brow * 128 + (kbo ^ ((brow & 7) << 4)));
            }
            #pragma unroll
            for (int fi = 0; fi < 2; fi++)
                #pragma unroll
                for (int fj = 0; fj < 2; fj++)
                    acc[fi][fj] = __builtin_amdgcn_mfma_f32_16x16x32_bf16(
                        af[fi], bf[fj], acc[fi][fj], 0, 0, 0);
        }
        asm volatile("s_barrier" ::: "memory");
        cur ^= 1;
    }
    long zoff = (long)bz * ga.sC;
    #pragma unroll
    for (int fi = 0; fi < 2; fi++)
        #pragma unroll
        for (int fj = 0; fj < 2; fj++)
            #pragma unroll
            for (int r = 0; r < 4; r++) {
                int row = m0 + wr * 32 + fi * 16 + ((lane >> 4) << 2) + r;
                int col = n0 + wc * 32 + fj * 16 + (lane & 15);
                gemm_epilogue_elem<BIASMODE, ACT, RESID, OUTMODE>(
                    acc[fi][fj][r], row, col, N, zoff, ga.bias, ga.Rres, ga.Cout,
                    ga.D1, ga.D2, ga.bias1, ga.bias2);
            }
}

// standalone wrapper
template <int BIASMODE, int ACT, bool RESID, int OUTMODE>
__global__ __launch_bounds__(256) void bgemm64_kernel(GArg ga) {
    __shared__ u16 As[2 * 4096];
    __shared__ u16 Bs[2 * 4096];
    bgemm64_body<BIASMODE, ACT, RESID, OUTMODE>(As, Bs, ga,
        blockIdx.x, blockIdx.y, blockIdx.z);
}

// merged pair: blocks [0,nblk0) run config a, rest run config b (independent GEMMs)
template <int B0, int A0, bool R0, int O0, int B1, int A1, bool R1, int O1>
__global__ __launch_bounds__(256) void gemm_pair_kernel(GArg a, int nblk0, GArg b) {
    __shared__ u16 As[2 * 4096];
    __shared__ u16 Bs[2 * 4096];
    int bid = blockIdx.x;
    if (bid < nblk0) {
        int xy = a.gx * a.gy;
        int bz = bid / xy, r = bid - bz * xy;
        bgemm64_body<B0, A0, R0, O0>(As, Bs, a, r % a.gx, r / a.gx, bz);
    } else {
        int bid2 = bid - nblk0;
        int xy = b.gx * b.gy;
        int bz = bid2 / xy, r = bid2 - bz * xy;
        bgemm64_body<B1, A1, R1, O1>(As, Bs, b, r % b.gx, r / b.gx, bz);
    }
}

// ---------------- fused MFMA flash attention: 8 waves, triple-buffered ----------
__global__ __launch_bounds__(512) void attn_mfma_kernel(
    const u16* __restrict__ Q, const u16* __restrict__ K,
    const u16* __restrict__ Vt, u16* __restrict__ O, int L, int S) {
    __shared__ __align__(16) u16 Ks[3][2048];
    __shared__ __align__(16) u16 Vs[3][2048];
    int bh = blockIdx.x;
    int b = bh >> 4, h = bh & 15;
    int tid = threadIdx.x;
    int lane = tid & 63, wv = tid >> 6;
    int q0 = blockIdx.y * 128 + wv * 16;
    int qr = lane & 15, g = lane >> 4, g8 = g * 8;
    int kperm = 8 * (qr >> 2) + (qr & 3);
    int nt = S >> 6;

    const u16* Kb = K + (long)b * S * 512 + h * 32;
    const u16* Vb = Vt + ((long)b * 512 + h * 32) * S;
    bshort8 qf = *(const bshort8*)(Q + ((long)(b * L + q0 + qr)) * 512 + h * 32 + g8);

    const u16* src;
    long step;
    char* d0;
    if (wv < 4) {
        int rk = wv * 16 + (lane >> 2);
        int f = ((rk >> 3) & 3) ^ ((rk >> 1) & 3);
        int sc = (lane & 3) ^ f;
        src = Kb + (long)rk * 512 + sc * 8;
        step = (long)64 * 512;
        d0 = (char*)Ks[0] + wv * 1024;
    } else {
        int rv = (wv - 4) * 8 + (lane >> 3);
        int sc = (lane & 7) ^ (lane >> 3);
        src = Vb + (long)rv * S + sc * 8;
        step = 64;
        d0 = (char*)Vs[0] + (wv - 4) * 1024;
    }

    f32x4 acc0 = {}, acc1 = {}, acc2 = {};
    const bshort8 onesf = { (short)0x3F80, (short)0x3F80, (short)0x3F80, (short)0x3F80,
                            (short)0x3F80, (short)0x3F80, (short)0x3F80, (short)0x3F80 };
    int f0 = (qr >> 2) ^ ((qr >> 1) & 1);
    int f1 = f0 ^ 2;

    gload_lds16(src, d0);
    gload_lds16(src + step, d0 + 4096);
    int cur = 0;
    for (int t = 0; t < nt; ++t) {
        if (t + 2 < nt) {
            int nb = cur + 2; if (nb >= 3) nb -= 3;
            gload_lds16(src + (long)(t + 2) * step, d0 + nb * 4096);
            asm volatile("s_waitcnt vmcnt(2)\ns_barrier" ::: "memory");
        } else if (t + 1 < nt) {
            asm volatile("s_waitcnt vmcnt(1)\ns_barrier" ::: "memory");
        } else {
            asm volatile("s_waitcnt vmcnt(0)\ns_barrier" ::: "memory");
        }
        const char* Kt = (const char*)Ks[0] + cur * 4096;
        const char* Vl = (const char*)Vs[0] + cur * 4096;
        bshort8 a0 = *(const bshort8*)(Kt + kperm * 64 + ((g ^ f0) << 4));
        bshort8 a1 = *(const bshort8*)(Kt + (kperm + 4) * 64 + ((g ^ f1) << 4));
        bshort8 a2 = *(const bshort8*)(Kt + (kperm + 32) * 64 + ((g ^ f0) << 4));
        bshort8 a3 = *(const bshort8*)(Kt + (kperm + 36) * 64 + ((g ^ f1) << 4));
        bshort8 v00 = *(const bshort8*)(Vl + qr * 128 + ((g ^ (qr & 7)) << 4));
        bshort8 v01 = *(const bshort8*)(Vl + qr * 128 + (((g + 4) ^ (qr & 7)) << 4));
        bshort8 v10 = *(const bshort8*)(Vl + (16 + qr) * 128 + ((g ^ (qr & 7)) << 4));
        bshort8 v11 = *(const bshort8*)(Vl + (16 + qr) * 128 + (((g + 4) ^ (qr & 7)) << 4));
        f32x4 zz = {0.f, 0.f, 0.f, 0.f};
        f32x4 st0 = __builtin_amdgcn_mfma_f32_16x16x32_bf16(a0, qf, zz, 0, 0, 0);
        f32x4 st1 = __builtin_amdgcn_mfma_f32_16x16x32_bf16(a1, qf, zz, 0, 0, 0);
        f32x4 st2 = __builtin_amdgcn_mfma_f32_16x16x32_bf16(a2, qf, zz, 0, 0, 0);
        f32x4 st3 = __builtin_amdgcn_mfma_f32_16x16x32_bf16(a3, qf, zz, 0, 0, 0);
        float p0[4], p1[4], p2[4], p3[4];
        #pragma unroll
        for (int r = 0; r < 4; r++) {
            p0[r] = exp2c(st0[r]);
            p1[r] = exp2c(st1[r]);
            p2[r] = exp2c(st2[r]);
            p3[r] = exp2c(st3[r]);
        }
        u32x4 P0 = { cvtpk(p0[0], p0[1]), cvtpk(p0[2], p0[3]),
                     cvtpk(p1[0], p1[1]), cvtpk(p1[2], p1[3]) };
        u32x4 P1 = { cvtpk(p2[0], p2[1]), cvtpk(p2[2], p2[3]),
                     cvtpk(p3[0], p3[1]), cvtpk(p3[2], p3[3]) };
        bshort8 pf0 = *(bshort8*)&P0;
        bshort8 pf1 = *(bshort8*)&P1;
        acc0 = __builtin_amdgcn_mfma_f32_16x16x32_bf16(v00, pf0, acc0, 0, 0, 0);
        acc0 = __builtin_amdgcn_mfma_f32_16x16x32_bf16(v01, pf1, acc0, 0, 0, 0);
        acc1 = __builtin_amdgcn_mfma_f32_16x16x32_bf16(v10, pf0, acc1, 0, 0, 0);
        acc1 = __builtin_amdgcn_mfma_f32_16x16x32_bf16(v11, pf1, acc1, 0, 0, 0);
        acc2 = __builtin_amdgcn_mfma_f32_16x16x32_bf16(onesf, pf0, acc2, 0, 0, 0);
        acc2 = __builtin_amdgcn_mfma_f32_16x16x32_bf16(onesf, pf1, acc2, 0, 0, 0);
        asm volatile("s_barrier" ::: "memory");
        cur = (cur == 2) ? 0 : cur + 1;
    }

    float inv = 1.f / acc2[0];  // every row of the ones-MFMA output = lsum(qr)
    u16* op = O + ((long)(b * L + q0 + qr)) * 512 + h * 32 + g * 4;
    sshort4 o0, o1;
    #pragma unroll
    for (int r = 0; r < 4; r++) {
        o0[r] = (short)f2b(acc0[r] * inv);
        o1[r] = (short)f2b(acc1[r] * inv);
    }
    *(sshort4*)op = o0;
    *(sshort4*)(op + 16) = o1;
}

// ---------------- layernorm over 512; fp32 + bf16 dual-store ----------------
__global__ __launch_bounds__(256) void ln_kernel(const float* __restrict__ X,
                                                 const float* __restrict__ g,
                                                 const float* __restrict__ bt,
                                                 float* __restrict__ Y,
                                                 u16* __restrict__ Yb) {
    int row = blockIdx.x;
    const float* xr = X + (long)row * 512;
    int t = threadIdx.x;
    float x0 = xr[t], x1 = xr[t + 256];
    float s = x0 + x1, ss = x0 * x0 + x1 * x1;
    #pragma unroll
    for (int off = 32; off > 0; off >>= 1) {
        s += __shfl_down(s, off);
        ss += __shfl_down(ss, off);
    }
    __shared__ float sred[4], ssred[4];
    int wid = t >> 6;
    if ((t & 63) == 0) { sred[wid] = s; ssred[wid] = ss; }
    __syncthreads();
    float ts = sred[0] + sred[1] + sred[2] + sred[3];
    float tss = ssred[0] + ssred[1] + ssred[2] + ssred[3];
    float mean = ts * (1.f / 512.f);
    float var = tss * (1.f / 512.f) - mean * mean;
    float rstd = rsqrtf(var + 1e-5f);
    float y0 = (x0 - mean) * rstd * g[t] + bt[t];
    float y1 = (x1 - mean) * rstd * g[t + 256] + bt[t + 256];
    Y[(long)row * 512 + t] = y0;
    Y[(long)row * 512 + t + 256] = y1;
    Yb[(long)row * 512 + t] = f2b(y0);
    Yb[(long)row * 512 + t + 256] = f2b(y1);
}

// ---------------- LN3 pass 1: per-row mean/rstd (one wave per row) ----------------
__global__ __launch_bounds__(256) void ln_stats_kernel(const float* __restrict__ X,
                                                       float2* __restrict__ stats) {
    int row = blockIdx.x * 4 + (threadIdx.x >> 6);
    int lane = threadIdx.x & 63;
    const float4* xr = (const float4*)(X + (long)row * 512) + lane * 2;
    float4 a = xr[0], b = xr[1];
    float s = (a.x + a.y) + (a.z + a.w) + (b.x + b.y) + (b.z + b.w);
    float ss = (a.x * a.x + a.y * a.y) + (a.z * a.z + a.w * a.w) +
               (b.x * b.x + b.y * b.y) + (b.z * b.z + b.w * b.w);
    #pragma unroll
    for (int off = 32; off > 0; off >>= 1) {
        s += __shfl_down(s, off);
        ss += __shfl_down(ss, off);
    }
    if (lane == 0) {
        float mean = s * (1.f / 512.f);
        float var = ss * (1.f / 512.f) - mean * mean;
        stats[row] = make_float2(mean, rsqrtf(var + 1e-5f));
    }
}

// ---------------- LN3 pass 2: LDS-tiled transpose + normalize -> [B,512,L] ----------
__global__ __launch_bounds__(256) void ln_trans_kernel(
    const float* __restrict__ X, const float2* __restrict__ stats,
    const float* __restrict__ g, const float* __restrict__ bt,
    float* __restrict__ Y) {
    __shared__ float T[64][65];
    int b = blockIdx.z, l0 = blockIdx.x * 64, c0 = blockIdx.y * 64;
    int t = threadIdx.x;
    int col = t & 63, rq = t >> 6;
    #pragma unroll
    for (int i = 0; i < 16; i++) {
        int row = i * 4 + rq;
        T[row][col] = X[((long)(b * 1024 + l0 + row)) * 512 + c0 + col];
    }
    __syncthreads();
    float2 mr = stats[b * 1024 + l0 + col];
    #pragma unroll
    for (int i = 0; i < 16; i++) {
        int c = i * 4 + rq;
        float val = (T[col][c] - mr.x) * mr.y * g[c0 + c] + bt[c0 + c];
        Y[((long)(b * 512 + c0 + c)) * 1024 + l0 + col] = val;
    }
}

extern "C" void kernel_launch(void* const* d_in, const int* in_sizes, int n_in,
                              void* d_out, int out_size, void* d_ws, size_t ws_size,
                              hipStream_t stream) {
    const float* x      = (const float*)d_in[0];
    const float* gfeat  = (const float*)d_in[1];
    const float* conv_w = (const float*)d_in[2];
    const float* conv_b = (const float*)d_in[3];
    const float* sa_wq = (const float*)d_in[4];
    const float* sa_bq = (const float*)d_in[5];
    const float* sa_bk = (const float*)d_in[7];
    const float* sa_bv = (const float*)d_in[9];
    const float* sa_bo = (const float*)d_in[11];
    const float* ca_bq = (const float*)d_in[13];
    const float* ca_bk = (const float*)d_in[15];
    const float* ca_bv = (const float*)d_in[17];
    const float* ca_bo = (const float*)d_in[19];
    const float* ffn_b1 = (const float*)d_in[21];
    const float* ffn_b2 = (const float*)d_in[23];
    const float* n1_g = (const float*)d_in[24];
    const float* n1_b = (const float*)d_in[25];
    const float* n2_g = (const float*)d_in[26];
    const float* n2_b = (const float*)d_in[27];
    const float* n3_g = (const float*)d_in[28];
    const float* n3_b = (const float*)d_in[29];
    (void)ws_size; (void)n_in; (void)in_sizes; (void)out_size;

    const long M_ = 1048576;
    float* W0 = (float*)d_ws;
    float* h   = W0;                 // [0, 2M) fp32
    float* hn  = W0 + 2 * M_;        // [2M, 4M) fp32
    u16* U = (u16*)(W0 + 4 * M_);
    u16* qb     = U;                 // 2M u16
    u16* kb     = U + 2 * M_;        // 2M
    u16* vtb    = U + 4 * M_;        // 2M   [4][512][1024]
    u16* k2b    = U + 6 * M_;        // 1M
    u16* v2tb   = U + 7 * M_;        // 1M   [4][512][512]
    u16* attb   = U + 8 * M_;        // 2M
    u16* hnb    = U + 10 * M_;       // 2M
    u16* midb   = U + 12 * M_;       // 8M
    u16* wsb    = U + 20 * M_;       // 6.55M
    u16* res_tb = U + 27 * M_;       // 1M (dead after conv; reused as LN3 stats)
    u16* crossb = U + 28 * M_;       // 1M

    float2* ln3_stats = (float2*)res_tb;

    const u16* conv_wb = wsb;
    const u16* sa_wqb = wsb + 262144;   // wq,wk,wv contiguous -> fused QKV weight
    const u16* sa_wob = wsb + 1048576;
    const u16* ca_wqb = wsb + 1310720;
    const u16* ca_wkb = wsb + 1572864;  // wk,wv contiguous -> fused KV weight
    const u16* ca_wob = wsb + 2097152;
    const u16* ffn1b = wsb + 2359296, *ffn2b = wsb + 3407872;
    const u16* xb = wsb + 4456448;

    // 0+1. fused: weights+x -> bf16 AND window reduce -> res_tb [b][n][c]
    WSrc ws;
    ws.p[0] = conv_w; ws.p[1] = sa_wq; ws.p[2] = (const float*)d_in[6];
    ws.p[3] = (const float*)d_in[8]; ws.p[4] = (const float*)d_in[10];
    ws.p[5] = (const float*)d_in[12]; ws.p[6] = (const float*)d_in[14];
    ws.p[7] = (const float*)d_in[16]; ws.p[8] = (const float*)d_in[18];
    ws.p[9] = (const float*)d_in[20]; ws.p[10] = (const float*)d_in[22];
    ws.p[11] = x;
    prep_kernel<<<6656, 256, 0, stream>>>(ws, wsb, gfeat, res_tb);

    // 2+3. MERGED: conv+relu (256 blk) + fused self-attn QKV proj (1536 blk)
    GArg convA = { conv_wb, res_tb, conv_b, nullptr, crossb, 512, 512,
                   0, 262144, 262144, nullptr, nullptr, nullptr, nullptr, 8, 8 };
    GArg qkvA  = { xb, sa_wqb, sa_bq, nullptr, qb, 1536, 512,
                   0, 0, 0, kb, vtb, sa_bk, sa_bv, 64, 24 };
    gemm_pair_kernel<2, 1, false, 1, 1, 0, false, 3><<<1792, 256, 0, stream>>>(
        convA, 256, qkvA);

    // 4. self attention (S=1024), single-pass -> attb bf16
    attn_mfma_kernel<<<dim3(64, 8), 512, 0, stream>>>(qb, kb, vtb, attb, 1024, 1024);

    // 5. out proj + resid x -> h fp32 (512 blocks)
    GArg op1 = { attb, sa_wob, sa_bo, x, h, 512, 512,
                 0, 0, 0, nullptr, nullptr, nullptr, nullptr, 64, 8 };
    bgemm64_kernel<1, 0, true, 0><<<dim3(64, 8), 256, 0, stream>>>(op1);

    // 6. LN1 -> hn fp32 + hnb bf16
    ln_kernel<<<4096, 256, 0, stream>>>(h, n1_g, n1_b, hn, hnb);

    // 7+8. MERGED: cross Q proj (512 blk) + fused K2/V2 proj (512 blk)
    GArg qA  = { hnb, ca_wqb, ca_bq, nullptr, qb, 512, 512,
                 0, 0, 0, nullptr, nullptr, nullptr, nullptr, 64, 8 };
    GArg kvA = { crossb, ca_wkb, ca_bk, nullptr, k2b, 1024, 512,
                 0, 0, 0, nullptr, v2tb, ca_bv, nullptr, 32, 16 };
    gemm_pair_kernel<1, 3, false, 1, 1, 0, false, 4><<<1024, 256, 0, stream>>>(
        qA, 512, kvA);

    // 9. cross attention (S=512), single-pass -> attb bf16
    attn_mfma_kernel<<<dim3(64, 8), 512, 0, stream>>>(qb, k2b, v2tb, attb, 1024, 512);

    // 10. out proj + resid hn -> h fp32
    GArg op2 = { attb, ca_wob, ca_bo, hn, h, 512, 512,
                 0, 0, 0, nullptr, nullptr, nullptr, nullptr, 64, 8 };
    bgemm64_kernel<1, 0, true, 0><<<dim3(64, 8), 256, 0, stream>>>(op2);

    // 11. LN2 -> hn fp32 + hnb bf16
    ln_kernel<<<4096, 256, 0, stream>>>(h, n2_g, n2_b, hn, hnb);

    // 12. FFN up + exact gelu -> midb bf16  [4096,2048] (2048 blocks)
    GArg f1 = { hnb, ffn1b, ffn_b1, nullptr, midb, 2048, 512,
                0, 0, 0, nullptr, nullptr, nullptr, nullptr, 64, 32 };
    bgemm64_kernel<1, 2, false, 1><<<dim3(64, 32), 256, 0, stream>>>(f1);

    // 13. FFN down + resid hn -> h fp32  [4096,512] K=2048
    GArg f2 = { midb, ffn2b, ffn_b2, hn, h, 512, 2048,
                0, 0, 0, nullptr, nullptr, nullptr, nullptr, 64, 8 };
    bgemm64_kernel<1, 0, true, 0><<<dim3(64, 8), 256, 0, stream>>>(f2);

    // 14. LN3: per-row stats, then LDS-tiled transpose -> d_out [B,512,L] fp32
    ln_stats_kernel<<<1024, 256, 0, stream>>>(h, ln3_stats);
    ln_trans_kernel<<<dim3(16, 8, 4), 256, 0, stream>>>(
        h, ln3_stats, n3_g, n3_b, (float*)d_out);
}

// Round 13
// 159.149 us; speedup vs baseline: 1.5616x; 1.0382x over previous
//
#include <hip/hip_runtime.h>
#include <hip/hip_bf16.h>
#include <math.h>

#define SCALE_Q 0.25504522f  // 1/sqrt(32) * log2(e)  (Q pre-scale for exp2 softmax)

typedef unsigned short u16;
typedef unsigned int u32;
typedef __attribute__((ext_vector_type(8))) short bshort8;
typedef __attribute__((ext_vector_type(4))) short sshort4;
typedef __attribute__((ext_vector_type(4))) float f32x4;
typedef __attribute__((ext_vector_type(4))) u32 u32x4;

__device__ inline u16 f2b(float f) {  // fp32 -> bf16 RNE
    union { float f; uint32_t u; } c;
    c.f = f;
    uint32_t u = c.u;
    return (u16)((u + 0x7fffu + ((u >> 16) & 1u)) >> 16);
}

__device__ __forceinline__ float b2f(u16 b) {
    union { u32 u; float f; } c;
    c.u = (u32)b << 16;
    return c.f;
}

__device__ __forceinline__ u32 cvtpk(float a, float b) {  // {lo=bf16(a), hi=bf16(b)}
    u32 r;
    asm("v_cvt_pk_bf16_f32 %0, %1, %2" : "=v"(r) : "v"(a), "v"(b));
    return r;
}

__device__ __forceinline__ float exp2c(float s) {  // 2^min(s,100)
    float c = fminf(s, 100.f);
    float r;
    asm("v_exp_f32 %0, %1" : "=v"(r) : "v"(c));
    return r;
}

__device__ inline void gload_lds16(const void* g, void* lds) {
    __builtin_amdgcn_global_load_lds(
        (const __attribute__((address_space(1))) void*)g,
        (__attribute__((address_space(3))) void*)lds, 16, 0, 0);
}

// ---------------- fused prep: bf16 convert (weights+x) AND window-reduce ----------
struct WSrc { const float* p[12]; };
__global__ __launch_bounds__(256) void prep_kernel(WSrc s, u16* __restrict__ dst,
                                                   const float* __restrict__ G,
                                                   u16* __restrict__ Rt) {
    int bid = blockIdx.x;
    if (bid < 256) {
        __shared__ u16 T[64][72];  // row stride 144B (16B-aligned)
        int b = bid >> 6, c0 = ((bid >> 3) & 7) << 6, n0 = (bid & 7) << 6;
        int t = threadIdx.x;
        int n = t & 63, cq = t >> 6;
        const float* Gb = G + (long)b * 512 * 4096;
        #pragma unroll
        for (int i = 0; i < 16; i++) {
            int c = i * 4 + cq;
            const float4* p = (const float4*)(Gb + (long)(c0 + c) * 4096 + (n0 + n) * 8);
            float4 a = p[0], bb = p[1];
            float mx = fmaxf(fmaxf(fmaxf(a.x, a.y), fmaxf(a.z, a.w)),
                             fmaxf(fmaxf(bb.x, bb.y), fmaxf(bb.z, bb.w)));
            float mn = fminf(fminf(fminf(a.x, a.y), fminf(a.z, a.w)),
                             fminf(fminf(bb.x, bb.y), fminf(bb.z, bb.w)));
            T[n][c] = f2b(fabsf(mx - mn) + 1e-6f);
        }
        __syncthreads();
        int nr = t >> 2, ck = (t & 3) << 4;
        u16* o = Rt + ((long)(b * 512 + n0 + nr) << 9) + c0 + ck;
        *(bshort8*)o = *(const bshort8*)&T[nr][ck];
        *(bshort8*)(o + 8) = *(const bshort8*)&T[nr][ck + 8];
    } else {
        long e = ((long)(bid - 256) * 256 + threadIdx.x) * 4;
        if (e >= 6553600) return;
        int w; long base;
        if (e < 2359296)      { w = (int)(e >> 18); base = (long)w << 18; }
        else if (e < 3407872) { w = 9;  base = 2359296; }
        else if (e < 4456448) { w = 10; base = 3407872; }
        else                  { w = 11; base = 4456448; }
        float4 v = *(const float4*)(s.p[w] + (e - base));
        dst[e + 0] = f2b(v.x); dst[e + 1] = f2b(v.y);
        dst[e + 2] = f2b(v.z); dst[e + 3] = f2b(v.w);
    }
}

// ================= GEMM arg bundle =================
struct GArg {
    const u16* A; const u16* Bt;
    const float* bias; const u16* Rres;   // residual read as bf16
    void* Cout;
    int N, K;
    long sA, sB, sC;
    u16* D1; u16* D2;
    const float* bias1; const float* bias2;
    int gx, gy;  // grid decode for pair dispatch
};

// ================= shared epilogue =================
template <int BIASMODE, int ACT, bool RESID, int OUTMODE>
__device__ __forceinline__ void gemm_epilogue_elem(
    float v, int row, int col, int N, long zoff,
    const float* bias, const u16* Rres, void* Cout,
    u16* D1, u16* D2, const float* bias1, const float* bias2) {
    if (OUTMODE == 3) {  // fused QKV split
        int grp = col >> 9, c = col & 511;
        float bb = (grp == 0) ? bias[c] : (grp == 1) ? bias1[c] : bias2[c];
        float vv = v + bb;
        if (grp == 0)
            ((u16*)Cout)[(long)row * 512 + c] = f2b(vv * SCALE_Q);
        else if (grp == 1)
            D1[(long)row * 512 + c] = f2b(vv);
        else
            D2[((long)((row >> 10) * 512 + c) << 10) + (row & 1023)] = f2b(vv);
    } else if (OUTMODE == 4) {  // fused KV split
        int grp = col >> 9, c = col & 511;
        float vv = v + ((grp == 0) ? bias[c] : bias1[c]);
        if (grp == 0)
            ((u16*)Cout)[(long)row * 512 + c] = f2b(vv);
        else
            D2[((long)((row >> 9) * 512 + c) << 9) + (row & 511)] = f2b(vv);
    } else {
        if (BIASMODE == 1) v += bias[col];
        if (BIASMODE == 2) v += bias[row];
        if (ACT == 1) v = fmaxf(v, 0.f);
        if (ACT == 2) v = 0.5f * v * (1.f + erff(v * 0.70710678118654752f));
        if (ACT == 3) v *= SCALE_Q;
        if (RESID) v += b2f(Rres[(long)row * N + col]);
        long off = zoff + (long)row * N + col;
        if (OUTMODE == 1) ((u16*)Cout)[off] = f2b(v);
        else              ((float*)Cout)[off] = v;
    }
}

// ---------------- bf16 MFMA GEMM body, 64x64 tile, dbuf counted-vmcnt ----------
template <int BIASMODE, int ACT, bool RESID, int OUTMODE>
__device__ __forceinline__ void bgemm64_body(
    u16* AsB, u16* BsB, const GArg& ga, int bx, int by, int bz) {
    const u16* A  = ga.A + (long)bz * ga.sA;
    const u16* Bt = ga.Bt + (long)bz * ga.sB;
    int K = ga.K, N = ga.N;
    int tid = threadIdx.x;
    int lane = tid & 63, wv = tid >> 6;
    int wr = wv >> 1, wc = wv & 1;
    int m0 = bx * 64, n0 = by * 64;
    f32x4 acc[2][2] = {};
    int srow = lane >> 3;
    int selem = ((lane & 7) ^ srow) << 3;

    auto STAGE = [&](int buf, int k0) {
        #pragma unroll
        for (int i = 0; i < 2; i++) {
            int roff = i * 32 + wv * 8;
            gload_lds16(A + (long)(m0 + roff + srow) * K + k0 + selem,
                        (char*)(AsB + buf * 4096) + roff * 128);
            gload_lds16(Bt + (long)(n0 + roff + srow) * K + k0 + selem,
                        (char*)(BsB + buf * 4096) + roff * 128);
        }
    };

    int NT = K >> 6;
    STAGE(0, 0);
    int cur = 0;
    for (int kt = 0; kt < NT; ++kt) {
        if (kt + 1 < NT) {
            STAGE(cur ^ 1, (kt + 1) << 6);
            asm volatile("s_waitcnt vmcnt(4)\ns_barrier" ::: "memory");
        } else {
            asm volatile("s_waitcnt vmcnt(0)\ns_barrier" ::: "memory");
        }
        const char* Asc = (const char*)(AsB + cur * 4096);
        const char* Bsc = (const char*)(BsB + cur * 4096);
        #pragma unroll
        for (int ks = 0; ks < 2; ks++) {
            bshort8 af[2], bf[2];
            int kbo = ks * 64 + ((lane >> 4) << 4);
            #pragma unroll
            for (int f = 0; f < 2; f++) {
                int arow = wr * 32 + f * 16 + (lane & 15);
                af[f] = *(const bshort8*)(Asc + arow * 128 + (kbo ^ ((arow & 7) << 4)));
                int brow = wc * 32 + f * 16 + (lane & 15);
                bf[f] = *(const bshort8*)(Bsc + brow * 128 + (kbo ^ ((brow & 7) << 4)));
            }
            #pragma unroll
            for (int fi = 0; fi < 2; fi++)
                #pragma unroll
                for (int fj = 0; fj < 2; fj++)
                    acc[fi][fj] = __builtin_amdgcn_mfma_f32_16x16x32_bf16(
                        af[fi], bf[fj], acc[fi][fj], 0, 0, 0);
        }
        asm volatile("s_barrier" ::: "memory");
        cur ^= 1;
    }
    long zoff = (long)bz * ga.sC;
    #pragma unroll
    for (int fi = 0; fi < 2; fi++)
        #pragma unroll
        for (int fj = 0; fj < 2; fj++)
            #pragma unroll
            for (int r = 0; r < 4; r++) {
                int row = m0 + wr * 32 + fi * 16 + ((lane >> 4) << 2) + r;
                int col = n0 + wc * 32 + fj * 16 + (lane & 15);
                gemm_epilogue_elem<BIASMODE, ACT, RESID, OUTMODE>(
                    acc[fi][fj][r], row, col, N, zoff, ga.bias, ga.Rres, ga.Cout,
                    ga.D1, ga.D2, ga.bias1, ga.bias2);
            }
}

// standalone wrapper
template <int BIASMODE, int ACT, bool RESID, int OUTMODE>
__global__ __launch_bounds__(256) void bgemm64_kernel(GArg ga) {
    __shared__ u16 As[2 * 4096];
    __shared__ u16 Bs[2 * 4096];
    bgemm64_body<BIASMODE, ACT, RESID, OUTMODE>(As, Bs, ga,
        blockIdx.x, blockIdx.y, blockIdx.z);
}

// merged pair: blocks [0,nblk0) run config a, rest run config b (independent GEMMs)
template <int B0, int A0, bool R0, int O0, int B1, int A1, bool R1, int O1>
__global__ __launch_bounds__(256) void gemm_pair_kernel(GArg a, int nblk0, GArg b) {
    __shared__ u16 As[2 * 4096];
    __shared__ u16 Bs[2 * 4096];
    int bid = blockIdx.x;
    if (bid < nblk0) {
        int xy = a.gx * a.gy;
        int bz = bid / xy, r = bid - bz * xy;
        bgemm64_body<B0, A0, R0, O0>(As, Bs, a, r % a.gx, r / a.gx, bz);
    } else {
        int bid2 = bid - nblk0;
        int xy = b.gx * b.gy;
        int bz = bid2 / xy, r = bid2 - bz * xy;
        bgemm64_body<B1, A1, R1, O1>(As, Bs, b, r % b.gx, r / b.gx, bz);
    }
}

// ---------------- fused MFMA flash attention: 8 waves, triple-buffered ----------
__global__ __launch_bounds__(512) void attn_mfma_kernel(
    const u16* __restrict__ Q, const u16* __restrict__ K,
    const u16* __restrict__ Vt, u16* __restrict__ O, int L, int S) {
    __shared__ __align__(16) u16 Ks[3][2048];
    __shared__ __align__(16) u16 Vs[3][2048];
    int bh = blockIdx.x;
    int b = bh >> 4, h = bh & 15;
    int tid = threadIdx.x;
    int lane = tid & 63, wv = tid >> 6;
    int q0 = blockIdx.y * 128 + wv * 16;
    int qr = lane & 15, g = lane >> 4, g8 = g * 8;
    int kperm = 8 * (qr >> 2) + (qr & 3);
    int nt = S >> 6;

    const u16* Kb = K + (long)b * S * 512 + h * 32;
    const u16* Vb = Vt + ((long)b * 512 + h * 32) * S;
    bshort8 qf = *(const bshort8*)(Q + ((long)(b * L + q0 + qr)) * 512 + h * 32 + g8);

    const u16* src;
    long step;
    char* d0;
    if (wv < 4) {
        int rk = wv * 16 + (lane >> 2);
        int f = ((rk >> 3) & 3) ^ ((rk >> 1) & 3);
        int sc = (lane & 3) ^ f;
        src = Kb + (long)rk * 512 + sc * 8;
        step = (long)64 * 512;
        d0 = (char*)Ks[0] + wv * 1024;
    } else {
        int rv = (wv - 4) * 8 + (lane >> 3);
        int sc = (lane & 7) ^ (lane >> 3);
        src = Vb + (long)rv * S + sc * 8;
        step = 64;
        d0 = (char*)Vs[0] + (wv - 4) * 1024;
    }

    f32x4 acc0 = {}, acc1 = {}, acc2 = {};
    const bshort8 onesf = { (short)0x3F80, (short)0x3F80, (short)0x3F80, (short)0x3F80,
                            (short)0x3F80, (short)0x3F80, (short)0x3F80, (short)0x3F80 };
    int f0 = (qr >> 2) ^ ((qr >> 1) & 1);
    int f1 = f0 ^ 2;

    gload_lds16(src, d0);
    gload_lds16(src + step, d0 + 4096);
    int cur = 0;
    for (int t = 0; t < nt; ++t) {
        if (t + 2 < nt) {
            int nb = cur + 2; if (nb >= 3) nb -= 3;
            gload_lds16(src + (long)(t + 2) * step, d0 + nb * 4096);
            asm volatile("s_waitcnt vmcnt(2)\ns_barrier" ::: "memory");
        } else if (t + 1 < nt) {
            asm volatile("s_waitcnt vmcnt(1)\ns_barrier" ::: "memory");
        } else {
            asm volatile("s_waitcnt vmcnt(0)\ns_barrier" ::: "memory");
        }
        const char* Kt = (const char*)Ks[0] + cur * 4096;
        const char* Vl = (const char*)Vs[0] + cur * 4096;
        bshort8 a0 = *(const bshort8*)(Kt + kperm * 64 + ((g ^ f0) << 4));
        bshort8 a1 = *(const bshort8*)(Kt + (kperm + 4) * 64 + ((g ^ f1) << 4));
        bshort8 a2 = *(const bshort8*)(Kt + (kperm + 32) * 64 + ((g ^ f0) << 4));
        bshort8 a3 = *(const bshort8*)(Kt + (kperm + 36) * 64 + ((g ^ f1) << 4));
        bshort8 v00 = *(const bshort8*)(Vl + qr * 128 + ((g ^ (qr & 7)) << 4));
        bshort8 v01 = *(const bshort8*)(Vl + qr * 128 + (((g + 4) ^ (qr & 7)) << 4));
        bshort8 v10 = *(const bshort8*)(Vl + (16 + qr) * 128 + ((g ^ (qr & 7)) << 4));
        bshort8 v11 = *(const bshort8*)(Vl + (16 + qr) * 128 + (((g + 4) ^ (qr & 7)) << 4));
        f32x4 zz = {0.f, 0.f, 0.f, 0.f};
        f32x4 st0 = __builtin_amdgcn_mfma_f32_16x16x32_bf16(a0, qf, zz, 0, 0, 0);
        f32x4 st1 = __builtin_amdgcn_mfma_f32_16x16x32_bf16(a1, qf, zz, 0, 0, 0);
        f32x4 st2 = __builtin_amdgcn_mfma_f32_16x16x32_bf16(a2, qf, zz, 0, 0, 0);
        f32x4 st3 = __builtin_amdgcn_mfma_f32_16x16x32_bf16(a3, qf, zz, 0, 0, 0);
        float p0[4], p1[4], p2[4], p3[4];
        #pragma unroll
        for (int r = 0; r < 4; r++) {
            p0[r] = exp2c(st0[r]);
            p1[r] = exp2c(st1[r]);
            p2[r] = exp2c(st2[r]);
            p3[r] = exp2c(st3[r]);
        }
        u32x4 P0 = { cvtpk(p0[0], p0[1]), cvtpk(p0[2], p0[3]),
                     cvtpk(p1[0], p1[1]), cvtpk(p1[2], p1[3]) };
        u32x4 P1 = { cvtpk(p2[0], p2[1]), cvtpk(p2[2], p2[3]),
                     cvtpk(p3[0], p3[1]), cvtpk(p3[2], p3[3]) };
        bshort8 pf0 = *(bshort8*)&P0;
        bshort8 pf1 = *(bshort8*)&P1;
        acc0 = __builtin_amdgcn_mfma_f32_16x16x32_bf16(v00, pf0, acc0, 0, 0, 0);
        acc0 = __builtin_amdgcn_mfma_f32_16x16x32_bf16(v01, pf1, acc0, 0, 0, 0);
        acc1 = __builtin_amdgcn_mfma_f32_16x16x32_bf16(v10, pf0, acc1, 0, 0, 0);
        acc1 = __builtin_amdgcn_mfma_f32_16x16x32_bf16(v11, pf1, acc1, 0, 0, 0);
        acc2 = __builtin_amdgcn_mfma_f32_16x16x32_bf16(onesf, pf0, acc2, 0, 0, 0);
        acc2 = __builtin_amdgcn_mfma_f32_16x16x32_bf16(onesf, pf1, acc2, 0, 0, 0);
        asm volatile("s_barrier" ::: "memory");
        cur = (cur == 2) ? 0 : cur + 1;
    }

    float inv = 1.f / acc2[0];  // every row of the ones-MFMA output = lsum(qr)
    u16* op = O + ((long)(b * L + q0 + qr)) * 512 + h * 32 + g * 4;
    sshort4 o0, o1;
    #pragma unroll
    for (int r = 0; r < 4; r++) {
        o0[r] = (short)f2b(acc0[r] * inv);
        o1[r] = (short)f2b(acc1[r] * inv);
    }
    *(sshort4*)op = o0;
    *(sshort4*)(op + 16) = o1;
}

// ---------------- layernorm over 512: bf16 in -> bf16 out ----------------
__global__ __launch_bounds__(256) void ln_kernel(const u16* __restrict__ X,
                                                 const float* __restrict__ g,
                                                 const float* __restrict__ bt,
                                                 u16* __restrict__ Yb) {
    int row = blockIdx.x;
    int t = threadIdx.x;
    u32 pack = ((const u32*)(X + (long)row * 512))[t];  // elems 2t, 2t+1
    float x0 = b2f((u16)(pack & 0xffff));
    float x1 = b2f((u16)(pack >> 16));
    float s = x0 + x1, ss = x0 * x0 + x1 * x1;
    #pragma unroll
    for (int off = 32; off > 0; off >>= 1) {
        s += __shfl_down(s, off);
        ss += __shfl_down(ss, off);
    }
    __shared__ float sred[4], ssred[4];
    int wid = t >> 6;
    if ((t & 63) == 0) { sred[wid] = s; ssred[wid] = ss; }
    __syncthreads();
    float ts = sred[0] + sred[1] + sred[2] + sred[3];
    float tss = ssred[0] + ssred[1] + ssred[2] + ssred[3];
    float mean = ts * (1.f / 512.f);
    float var = tss * (1.f / 512.f) - mean * mean;
    float rstd = rsqrtf(var + 1e-5f);
    float y0 = (x0 - mean) * rstd * g[2 * t] + bt[2 * t];
    float y1 = (x1 - mean) * rstd * g[2 * t + 1] + bt[2 * t + 1];
    ((u32*)(Yb + (long)row * 512))[t] = cvtpk(y0, y1);
}

// ---------------- LN3 pass 1: per-row mean/rstd from bf16 (one wave per row) --------
__global__ __launch_bounds__(256) void ln_stats_kernel(const u16* __restrict__ X,
                                                       float2* __restrict__ stats) {
    int row = blockIdx.x * 4 + (threadIdx.x >> 6);
    int lane = threadIdx.x & 63;
    bshort8 v = *(const bshort8*)(X + (long)row * 512 + lane * 8);
    float s = 0.f, ss = 0.f;
    #pragma unroll
    for (int i = 0; i < 8; i++) {
        float f = b2f((u16)v[i]);
        s += f;
        ss += f * f;
    }
    #pragma unroll
    for (int off = 32; off > 0; off >>= 1) {
        s += __shfl_down(s, off);
        ss += __shfl_down(ss, off);
    }
    if (lane == 0) {
        float mean = s * (1.f / 512.f);
        float var = ss * (1.f / 512.f) - mean * mean;
        stats[row] = make_float2(mean, rsqrtf(var + 1e-5f));
    }
}

// ---------------- LN3 pass 2: LDS-tiled transpose + normalize -> [B,512,L] fp32 -----
__global__ __launch_bounds__(256) void ln_trans_kernel(
    const u16* __restrict__ X, const float2* __restrict__ stats,
    const float* __restrict__ g, const float* __restrict__ bt,
    float* __restrict__ Y) {
    __shared__ u16 T[64][66];  // stride 33 dwords == 1 mod 32 -> conflict-free
    int b = blockIdx.z, l0 = blockIdx.x * 64, c0 = blockIdx.y * 64;
    int t = threadIdx.x;
    int col = t & 63, rq = t >> 6;
    #pragma unroll
    for (int i = 0; i < 16; i++) {
        int row = i * 4 + rq;
        T[row][col] = X[((long)(b * 1024 + l0 + row)) * 512 + c0 + col];
    }
    __syncthreads();
    float2 mr = stats[b * 1024 + l0 + col];
    #pragma unroll
    for (int i = 0; i < 16; i++) {
        int c = i * 4 + rq;
        float val = (b2f(T[col][c]) - mr.x) * mr.y * g[c0 + c] + bt[c0 + c];
        Y[((long)(b * 512 + c0 + c)) * 1024 + l0 + col] = val;
    }
}

extern "C" void kernel_launch(void* const* d_in, const int* in_sizes, int n_in,
                              void* d_out, int out_size, void* d_ws, size_t ws_size,
                              hipStream_t stream) {
    const float* x      = (const float*)d_in[0];
    const float* gfeat  = (const float*)d_in[1];
    const float* conv_w = (const float*)d_in[2];
    const float* conv_b = (const float*)d_in[3];
    const float* sa_wq = (const float*)d_in[4];
    const float* sa_bq = (const float*)d_in[5];
    const float* sa_bk = (const float*)d_in[7];
    const float* sa_bv = (const float*)d_in[9];
    const float* sa_bo = (const float*)d_in[11];
    const float* ca_bq = (const float*)d_in[13];
    const float* ca_bk = (const float*)d_in[15];
    const float* ca_bv = (const float*)d_in[17];
    const float* ca_bo = (const float*)d_in[19];
    const float* ffn_b1 = (const float*)d_in[21];
    const float* ffn_b2 = (const float*)d_in[23];
    const float* n1_g = (const float*)d_in[24];
    const float* n1_b = (const float*)d_in[25];
    const float* n2_g = (const float*)d_in[26];
    const float* n2_b = (const float*)d_in[27];
    const float* n3_g = (const float*)d_in[28];
    const float* n3_b = (const float*)d_in[29];
    (void)ws_size; (void)n_in; (void)in_sizes; (void)out_size;

    const long M_ = 1048576;
    float* W0 = (float*)d_ws;
    u16* hb    = (u16*)W0;           // [0, 1M floats) as 2M bf16 (4096x512)
    u16* U = (u16*)(W0 + 4 * M_);
    u16* qb     = U;                 // 2M u16
    u16* kb     = U + 2 * M_;        // 2M
    u16* vtb    = U + 4 * M_;        // 2M   [4][512][1024]
    u16* k2b    = U + 6 * M_;        // 1M
    u16* v2tb   = U + 7 * M_;        // 1M   [4][512][512]
    u16* attb   = U + 8 * M_;        // 2M
    u16* hnb    = U + 10 * M_;       // 2M
    u16* midb   = U + 12 * M_;       // 8M
    u16* wsb    = U + 20 * M_;       // 6.55M
    u16* res_tb = U + 27 * M_;       // 1M (dead after conv; reused as LN3 stats)
    u16* crossb = U + 28 * M_;       // 1M

    float2* ln3_stats = (float2*)res_tb;

    const u16* conv_wb = wsb;
    const u16* sa_wqb = wsb + 262144;   // wq,wk,wv contiguous -> fused QKV weight
    const u16* sa_wob = wsb + 1048576;
    const u16* ca_wqb = wsb + 1310720;
    const u16* ca_wkb = wsb + 1572864;  // wk,wv contiguous -> fused KV weight
    const u16* ca_wob = wsb + 2097152;
    const u16* ffn1b = wsb + 2359296, *ffn2b = wsb + 3407872;
    const u16* xb = wsb + 4456448;

    // 0+1. fused: weights+x -> bf16 AND window reduce -> res_tb [b][n][c]
    WSrc ws;
    ws.p[0] = conv_w; ws.p[1] = sa_wq; ws.p[2] = (const float*)d_in[6];
    ws.p[3] = (const float*)d_in[8]; ws.p[4] = (const float*)d_in[10];
    ws.p[5] = (const float*)d_in[12]; ws.p[6] = (const float*)d_in[14];
    ws.p[7] = (const float*)d_in[16]; ws.p[8] = (const float*)d_in[18];
    ws.p[9] = (const float*)d_in[20]; ws.p[10] = (const float*)d_in[22];
    ws.p[11] = x;
    prep_kernel<<<6656, 256, 0, stream>>>(ws, wsb, gfeat, res_tb);

    // 2+3. MERGED: conv+relu (256 blk) + fused self-attn QKV proj (1536 blk)
    GArg convA = { conv_wb, res_tb, conv_b, nullptr, crossb, 512, 512,
                   0, 262144, 262144, nullptr, nullptr, nullptr, nullptr, 8, 8 };
    GArg qkvA  = { xb, sa_wqb, sa_bq, nullptr, qb, 1536, 512,
                   0, 0, 0, kb, vtb, sa_bk, sa_bv, 64, 24 };
    gemm_pair_kernel<2, 1, false, 1, 1, 0, false, 3><<<1792, 256, 0, stream>>>(
        convA, 256, qkvA);

    // 4. self attention (S=1024), single-pass -> attb bf16
    attn_mfma_kernel<<<dim3(64, 8), 512, 0, stream>>>(qb, kb, vtb, attb, 1024, 1024);

    // 5. out proj + resid xb -> hb bf16 (512 blocks)
    GArg op1 = { attb, sa_wob, sa_bo, xb, hb, 512, 512,
                 0, 0, 0, nullptr, nullptr, nullptr, nullptr, 64, 8 };
    bgemm64_kernel<1, 0, true, 1><<<dim3(64, 8), 256, 0, stream>>>(op1);

    // 6. LN1 -> hnb bf16
    ln_kernel<<<4096, 256, 0, stream>>>(hb, n1_g, n1_b, hnb);

    // 7+8. MERGED: cross Q proj (512 blk) + fused K2/V2 proj (512 blk)
    GArg qA  = { hnb, ca_wqb, ca_bq, nullptr, qb, 512, 512,
                 0, 0, 0, nullptr, nullptr, nullptr, nullptr, 64, 8 };
    GArg kvA = { crossb, ca_wkb, ca_bk, nullptr, k2b, 1024, 512,
                 0, 0, 0, nullptr, v2tb, ca_bv, nullptr, 32, 16 };
    gemm_pair_kernel<1, 3, false, 1, 1, 0, false, 4><<<1024, 256, 0, stream>>>(
        qA, 512, kvA);

    // 9. cross attention (S=512), single-pass -> attb bf16
    attn_mfma_kernel<<<dim3(64, 8), 512, 0, stream>>>(qb, k2b, v2tb, attb, 1024, 512);

    // 10. out proj + resid hnb -> hb bf16
    GArg op2 = { attb, ca_wob, ca_bo, hnb, hb, 512, 512,
                 0, 0, 0, nullptr, nullptr, nullptr, nullptr, 64, 8 };
    bgemm64_kernel<1, 0, true, 1><<<dim3(64, 8), 256, 0, stream>>>(op2);

    // 11. LN2 -> hnb bf16 (overwrites LN1's, no longer needed)
    ln_kernel<<<4096, 256, 0, stream>>>(hb, n2_g, n2_b, hnb);

    // 12. FFN up + exact gelu -> midb bf16  [4096,2048] (2048 blocks)
    GArg f1 = { hnb, ffn1b, ffn_b1, nullptr, midb, 2048, 512,
                0, 0, 0, nullptr, nullptr, nullptr, nullptr, 64, 32 };
    bgemm64_kernel<1, 2, false, 1><<<dim3(64, 32), 256, 0, stream>>>(f1);

    // 13. FFN down + resid hnb -> hb bf16  [4096,512] K=2048
    GArg f2 = { midb, ffn2b, ffn_b2, hnb, hb, 512, 2048,
                0, 0, 0, nullptr, nullptr, nullptr, nullptr, 64, 8 };
    bgemm64_kernel<1, 0, true, 1><<<dim3(64, 8), 256, 0, stream>>>(f2);

    // 14. LN3: per-row stats (bf16 in), then LDS-tiled transpose -> d_out fp32
    ln_stats_kernel<<<1024, 256, 0, stream>>>(hb, ln3_stats);
    ln_trans_kernel<<<dim3(16, 8, 4), 256, 0, stream>>>(
        hb, ln3_stats, n3_g, n3_b, (float*)d_out);
}